// Round 13
// baseline (508.409 us; speedup 1.0000x reference)
//
#include <hip/hip_runtime.h>

// ---------------- dims ----------------
constexpr int HH    = 64;     // heads
constexpr int PP    = 64;     // head dim
constexpr int HID   = 2048;
constexpr int NST   = 128;    // state dim
constexpr int LCC   = 256;    // chunk len
constexpr int INTER = 4096;
constexpr int CONVD = 4352;
constexpr int PROJD = 8512;
constexpr int BB    = 4;
constexpr int SS    = 1024;
constexpr int NC    = 4;      // chunks
constexpr int MR    = BB * SS;      // 4096 rows
constexpr int NPAD1 = 8576;         // PROJD padded to 128 (GEMM1 tiles: 67)

typedef unsigned short u16;
typedef __bf16 bf16x8_t __attribute__((ext_vector_type(8)));
typedef short short8 __attribute__((ext_vector_type(8)));
typedef float f32x4 __attribute__((ext_vector_type(4)));
typedef u16 u16x4 __attribute__((ext_vector_type(4)));

__device__ __forceinline__ float bf2f(u16 u) {
  union { unsigned int i; float f; } v; v.i = ((unsigned int)u) << 16; return v.f;
}
__device__ __forceinline__ u16 f2bf(float f) {
  union { float f; unsigned int i; } v; v.f = f;
  unsigned int r = v.i + 0x7FFFu + ((v.i >> 16) & 1u);
  return (u16)(r >> 16);
}
__device__ __forceinline__ f32x4 mfma16(short8 a, short8 b, f32x4 c) {
  union U { short8 s; bf16x8_t b; };
  U ua; ua.s = a; U ub; ub.s = b;
  return __builtin_amdgcn_mfma_f32_16x16x32_bf16(ua.b, ub.b, c, 0, 0, 0);
}
__device__ __forceinline__ float sigm(float x) { return 1.f / (1.f + __expf(-x)); }
__device__ __forceinline__ void gload16(const u16* g, u16* l) {
  __builtin_amdgcn_global_load_lds(
      (const __attribute__((address_space(1))) void*)g,
      (__attribute__((address_space(3))) void*)l, 16, 0, 0);
}

// ---------------- fp32 -> bf16 convert (hs) ------------------------------------
__global__ void f32_to_bf16(const float* __restrict__ in, u16* __restrict__ out) {
  int i = (blockIdx.x * 256 + threadIdx.x) * 8;
  float4 a = *(const float4*)&in[i];
  float4 b = *(const float4*)&in[i + 4];
  short8 v;
  v[0] = (short)f2bf(a.x); v[1] = (short)f2bf(a.y);
  v[2] = (short)f2bf(a.z); v[3] = (short)f2bf(a.w);
  v[4] = (short)f2bf(b.x); v[5] = (short)f2bf(b.y);
  v[6] = (short)f2bf(b.z); v[7] = (short)f2bf(b.w);
  *(short8*)&out[i] = v;
}

// ---------------- vectorized weight transpose: in [K][N] f32 -> out [Npad][K] bf16
__global__ __launch_bounds__(256) void transpose_w64(
    const float* __restrict__ in, u16* __restrict__ out, int K_, int N_) {
  const int n0 = blockIdx.x * 64, k0 = blockIdx.y * 64;
  const int t = threadIdx.x;
  __shared__ u16 tile[64][72];   // [n][k]
#pragma unroll
  for (int i = 0; i < 4; ++i) {
    int idx = i * 256 + t;            // 0..1023
    int kk = idx >> 4;                // 0..63
    int nc = (idx & 15) * 4;          // 0..60
    int n = n0 + nc;
    float4 v = make_float4(0.f, 0.f, 0.f, 0.f);
    if (n + 3 < N_) v = *(const float4*)&in[(size_t)(k0 + kk) * N_ + n];
    tile[nc + 0][kk] = f2bf(v.x);
    tile[nc + 1][kk] = f2bf(v.y);
    tile[nc + 2][kk] = f2bf(v.z);
    tile[nc + 3][kk] = f2bf(v.w);
  }
  __syncthreads();
#pragma unroll
  for (int i = 0; i < 2; ++i) {
    int idx = i * 256 + t;            // 0..511
    int nn = idx >> 3;                // 0..63
    int kc = (idx & 7) * 8;
    *(short8*)&out[(size_t)(n0 + nn) * K_ + k0 + kc] =
        *(const short8*)&tile[nn][kc];
  }
}

// ---------------- generic bf16 transpose (B only): in [R][C] -> out [C][R] -----
__global__ void transpose_bf16(const u16* __restrict__ in, u16* __restrict__ out,
                               int R, int C) {
  int bt = blockIdx.z;
  const u16* ip = in + (size_t)bt * R * C;
  u16* op = out + (size_t)bt * R * C;
  __shared__ u16 tile[32][33];
  int r0 = blockIdx.y * 32, c0 = blockIdx.x * 32, t = threadIdx.x;
#pragma unroll
  for (int i = 0; i < 4; ++i) {
    int flat = i * 256 + t; int rr = flat >> 5, cc = flat & 31;
    tile[rr][cc] = ip[(size_t)(r0 + rr) * C + c0 + cc];
  }
  __syncthreads();
#pragma unroll
  for (int i = 0; i < 4; ++i) {
    int flat = i * 256 + t; int cc = flat >> 5, rr = flat & 31;
    op[(size_t)(c0 + cc) * R + r0 + rr] = tile[rr][cc];
  }
}

// ---------------- GEMM1 (proven R4): split bf16 epilogue -----------------------
__global__ __launch_bounds__(256) void gemm_bt1(
    const u16* __restrict__ A, const u16* __restrict__ Bt,
    const float* __restrict__ bias, u16* __restrict__ gateb,
    u16* __restrict__ hbcb, u16* __restrict__ dtsec,
    int Nreal, int K, int gx) {
  __shared__ __align__(16) u16 As[128 * 64];
  __shared__ __align__(16) u16 Bs[128 * 64];
  const int nwg = gridDim.x, bid = blockIdx.x;
  const int q = nwg >> 3;
  const int swz = (bid & 7) * q + (bid >> 3);
  const int bx = swz % gx, by = swz / gx;
  const int m0 = by * 128, n0 = bx * 128;
  const int t = threadIdx.x;
  const int w = t >> 6, lane = t & 63, lr = lane & 15, lhi = lane >> 4;
  const int wr = (w >> 1) * 64, wc = (w & 1) * 64;
  const int srow = t >> 3;
  const int sw_scol = (((t & 7) ^ ((t >> 3) & 7)) << 3);
  const u16* ga = A + (size_t)(m0 + srow) * K + sw_scol;
  const u16* gb = Bt + (size_t)(n0 + srow) * K + sw_scol;
  u16* la = As + w * 512;
  u16* lb = Bs + w * 512;
  const int swz_rd = (lr & 7) << 3;
  f32x4 acc[4][4] = {};
  for (int k0 = 0; k0 < K; k0 += 64) {
    __syncthreads();
#pragma unroll
    for (int j = 0; j < 4; ++j) {
      gload16(ga + (size_t)(j * 32) * K + k0, la + j * 2048);
      gload16(gb + (size_t)(j * 32) * K + k0, lb + j * 2048);
    }
    __syncthreads();
#pragma unroll
    for (int ks = 0; ks < 2; ++ks) {
      const int cs = (ks * 32 + lhi * 8) ^ swz_rd;
      short8 af[4], bfv[4];
#pragma unroll
      for (int mi = 0; mi < 4; ++mi)
        af[mi] = *(const short8*)&As[(wr + mi * 16 + lr) * 64 + cs];
#pragma unroll
      for (int ni = 0; ni < 4; ++ni)
        bfv[ni] = *(const short8*)&Bs[(wc + ni * 16 + lr) * 64 + cs];
#pragma unroll
      for (int mi = 0; mi < 4; ++mi)
#pragma unroll
        for (int ni = 0; ni < 4; ++ni)
          acc[mi][ni] = mfma16(af[mi], bfv[ni], acc[mi][ni]);
    }
  }
#pragma unroll
  for (int ni = 0; ni < 4; ++ni) {
    int col = n0 + wc + ni * 16 + lr;
    if (col >= Nreal) continue;
    float bv = bias[col];
#pragma unroll
    for (int mi = 0; mi < 4; ++mi)
#pragma unroll
      for (int j = 0; j < 4; ++j) {
        int row = m0 + wr + mi * 16 + lhi * 4 + j;
        float v = acc[mi][ni][j] + bv;
        u16 o = f2bf(v);
        if (col < INTER)              gateb[(size_t)row * INTER + col] = o;
        else if (col < INTER + CONVD) hbcb[(size_t)row * CONVD + (col - INTER)] = o;
        else                          dtsec[(size_t)row * HH + (col - INTER - CONVD)] = o;
      }
  }
}

// ---------------- GEMM2 split-K x2: grid 1024, kz in {0,1} ---------------------
// kz=0 -> out (+bias); kz=1 -> partial buffer (no bias). fixup adds.
__global__ __launch_bounds__(256) void gemm2_sk(
    const u16* __restrict__ A, const u16* __restrict__ Bt,
    const float* __restrict__ bias, float* __restrict__ outp,
    float* __restrict__ part) {
  __shared__ __align__(16) u16 As[128 * 64];
  __shared__ __align__(16) u16 Bs[128 * 64];
  const int bid = blockIdx.x;                 // 1024 blocks
  const int swz = (bid & 7) * 128 + (bid >> 3);
  const int bx = swz & 15;                    // N tile (16)
  const int rest = swz >> 4;
  const int by = rest & 31;                   // M tile (32)
  const int kz = rest >> 5;                   // K split (2)
  const int m0 = by * 128, n0 = bx * 128;
  const int K = INTER;                        // full row stride 4096
  const int kbeg = kz * 2048, kend = kbeg + 2048;
  const int t = threadIdx.x;
  const int w = t >> 6, lane = t & 63, lr = lane & 15, lhi = lane >> 4;
  const int wr = (w >> 1) * 64, wc = (w & 1) * 64;
  const int srow = t >> 3;
  const int sw_scol = (((t & 7) ^ ((t >> 3) & 7)) << 3);
  const u16* ga = A + (size_t)(m0 + srow) * K + sw_scol;
  const u16* gb = Bt + (size_t)(n0 + srow) * K + sw_scol;
  u16* la = As + w * 512;
  u16* lb = Bs + w * 512;
  const int swz_rd = (lr & 7) << 3;
  f32x4 acc[4][4] = {};
  for (int k0 = kbeg; k0 < kend; k0 += 64) {
    __syncthreads();
#pragma unroll
    for (int j = 0; j < 4; ++j) {
      gload16(ga + (size_t)(j * 32) * K + k0, la + j * 2048);
      gload16(gb + (size_t)(j * 32) * K + k0, lb + j * 2048);
    }
    __syncthreads();
#pragma unroll
    for (int ks = 0; ks < 2; ++ks) {
      const int cs = (ks * 32 + lhi * 8) ^ swz_rd;
      short8 af[4], bfv[4];
#pragma unroll
      for (int mi = 0; mi < 4; ++mi)
        af[mi] = *(const short8*)&As[(wr + mi * 16 + lr) * 64 + cs];
#pragma unroll
      for (int ni = 0; ni < 4; ++ni)
        bfv[ni] = *(const short8*)&Bs[(wc + ni * 16 + lr) * 64 + cs];
#pragma unroll
      for (int mi = 0; mi < 4; ++mi)
#pragma unroll
        for (int ni = 0; ni < 4; ++ni)
          acc[mi][ni] = mfma16(af[mi], bfv[ni], acc[mi][ni]);
    }
  }
  float* dst = (kz == 0) ? outp : part;
#pragma unroll
  for (int ni = 0; ni < 4; ++ni) {
    int col = n0 + wc + ni * 16 + lr;
    float bv = (kz == 0) ? bias[col] : 0.f;
#pragma unroll
    for (int mi = 0; mi < 4; ++mi)
#pragma unroll
      for (int j = 0; j < 4; ++j) {
        int row = m0 + wr + mi * 16 + lhi * 4 + j;
        dst[(size_t)row * HID + col] = acc[mi][ni][j] + bv;
      }
  }
}

// ---------------- fixup: out += part (float4) ----------------------------------
__global__ void addbuf(float* __restrict__ outp, const float* __restrict__ part) {
  int i = (blockIdx.x * 256 + threadIdx.x) * 4;
  float4 a = *(const float4*)&outp[i];
  float4 b = *(const float4*)&part[i];
  a.x += b.x; a.y += b.y; a.z += b.z; a.w += b.w;
  *(float4*)&outp[i] = a;
}

// ---------------- conv1d X-part + SiLU, fused transpose dual-write -------------
__global__ __launch_bounds__(256) void conv_x(
    const u16* __restrict__ hbcb, const float* __restrict__ convw,
    u16* __restrict__ X_lp, u16* __restrict__ Xt) {
  const int st = blockIdx.x, h = blockIdx.y, b = blockIdx.z;
  const int s0 = st * 64;
  const int t = threadIdx.x;
  const int bh = b * HH + h;
  __shared__ u16 tile[64][72];   // [s][p]
#pragma unroll
  for (int i = 0; i < 2; ++i) {
    int idx = i * 256 + t;       // 0..511
    int s = idx >> 3;            // 0..63
    int pc = (idx & 7) * 8;
    short8 v[4];
#pragma unroll
    for (int k = 0; k < 4; ++k) {
      int ss = s0 + s - 3 + k;
      if (ss >= 0)
        v[k] = *(const short8*)&hbcb[(size_t)(b * SS + ss) * CONVD + h * 64 + pc];
      else
        v[k] = short8{0, 0, 0, 0, 0, 0, 0, 0};
    }
    short8 o;
#pragma unroll
    for (int j = 0; j < 8; ++j) {
      float4 wj = *(const float4*)&convw[(h * 64 + pc + j) * 4];
      float a = bf2f((u16)v[0][j]) * wj.x + bf2f((u16)v[1][j]) * wj.y +
                bf2f((u16)v[2][j]) * wj.z + bf2f((u16)v[3][j]) * wj.w;
      o[j] = (short)f2bf(a * sigm(a));
    }
    *(short8*)&X_lp[((size_t)bh * SS + s0 + s) * PP + pc] = o;
    *(short8*)&tile[s][pc] = o;
  }
  __syncthreads();
#pragma unroll
  for (int i = 0; i < 2; ++i) {
    int idx = i * 256 + t;
    int p = idx >> 3;            // 0..63
    int sc = (idx & 7) * 8;
    short8 o;
#pragma unroll
    for (int j = 0; j < 8; ++j) o[j] = (short)tile[sc + j][p];
    *(short8*)&Xt[((size_t)bh * PP + p) * SS + s0 + sc] = o;
  }
}

// ---------------- conv1d B/C channels (256 ch = 32 chunks of 8) + SiLU ---------
__global__ __launch_bounds__(256) void conv_bc(
    const u16* __restrict__ hbcb, const float* __restrict__ convw,
    u16* __restrict__ Bc, u16* __restrict__ Cc) {
  int idx = blockIdx.x * 256 + threadIdx.x;   // < BB*SS*32
  int c8 = idx & 31;
  int rest = idx >> 5;
  int s = rest & (SS - 1);
  int b = rest >> 10;
  int ch = INTER + c8 * 8;                    // [4096, 4352)
  short8 v[4];
#pragma unroll
  for (int k = 0; k < 4; ++k) {
    int ss = s - 3 + k;
    if (ss >= 0) v[k] = *(const short8*)&hbcb[(size_t)(b * SS + ss) * CONVD + ch];
    else         v[k] = short8{0, 0, 0, 0, 0, 0, 0, 0};
  }
  short8 o;
#pragma unroll
  for (int j = 0; j < 8; ++j) {
    float4 wj = *(const float4*)&convw[(ch + j) * 4];
    float a = bf2f((u16)v[0][j]) * wj.x + bf2f((u16)v[1][j]) * wj.y +
              bf2f((u16)v[2][j]) * wj.z + bf2f((u16)v[3][j]) * wj.w;
    o[j] = (short)f2bf(a * sigm(a));
  }
  if (ch < INTER + NST)
    *(short8*)&Bc[((size_t)(b * SS + s)) * NST + (ch - INTER)] = o;
  else
    *(short8*)&Cc[((size_t)(b * SS + s)) * NST + (ch - INTER - NST)] = o;
}

// ---------------- fused dt softplus + per-chunk cumsum (wave scan) -------------
__global__ __launch_bounds__(256) void dt_cumsum(
    const u16* __restrict__ dtsec, const float* __restrict__ dtb,
    const float* __restrict__ alog, float* __restrict__ dtv,
    float* __restrict__ cumA) {
  const int bh = blockIdx.x;
  const int b = bh >> 6, h = bh & 63;
  const int t = threadIdx.x, w = t >> 6, lane = t & 63;
  const float na = -__expf(alog[h]);
  const float db = dtb[h];
  size_t base = (size_t)bh * SS + w * LCC;
  float d[4];
#pragma unroll
  for (int j = 0; j < 4; ++j) {
    int s = w * LCC + lane * 4 + j;
    float x = bf2f(dtsec[(size_t)(b * SS + s) * HH + h]) + db;
    d[j] = (x > 20.f) ? x : log1pf(__expf(x));
  }
  *(float4*)&dtv[base + lane * 4] = make_float4(d[0], d[1], d[2], d[3]);
  float a0 = na * d[0];
  float s1 = a0 + na * d[1];
  float s2 = s1 + na * d[2];
  float tot = s2 + na * d[3];
  float run = tot;
#pragma unroll
  for (int off = 1; off < 64; off <<= 1) {
    float u = __shfl_up(run, off);
    if (lane >= off) run += u;
  }
  float excl = run - tot;
  float4 o; o.x = excl + a0; o.y = excl + s1; o.z = excl + s2; o.w = excl + tot;
  *(float4*)&cumA[base + lane * 4] = o;
}

// ---------------- SSD pass 1: Y_diag + D residual + chunk states (decay-skip) --
__global__ __launch_bounds__(256) void ssd1(
    const u16* __restrict__ Cc, const u16* __restrict__ Bc,
    const u16* __restrict__ Btc, const u16* __restrict__ Xt,
    const u16* __restrict__ X_lp, const float* __restrict__ Dv,
    const float* __restrict__ cumA, const float* __restrict__ dtv,
    u16* __restrict__ ybb, u16* __restrict__ statesb) {
  const int h = blockIdx.x, c = blockIdx.y, b = blockIdx.z;
  const int bh = b * HH + h, s0 = c * LCC;
  const int t = threadIdx.x, w = t >> 6, lane = t & 63, lr = lane & 15, lhi = lane >> 4;
  __shared__ float cumA_s[LCC], dtv_s[LCC], w_s[LCC];
  __shared__ __align__(16) u16 Mld[4][64 * 72];
  cumA_s[t] = cumA[(size_t)bh * SS + s0 + t];
  dtv_s[t] = dtv[(size_t)bh * SS + s0 + t];
  __syncthreads();
  w_s[t] = dtv_s[t] * __expf(cumA_s[LCC - 1] - cumA_s[t]);
  __syncthreads();

  f32x4 Yacc[4][4] = {};
  u16* Mw = &Mld[w][0];
  for (int st = 0; st <= w; ++st) {
    if (st < w && (cumA_s[w * 64] - cumA_s[st * 64 + 63] < -30.f)) continue;
    f32x4 G[4][4] = {};
#pragma unroll
    for (int ks = 0; ks < 4; ++ks) {
      short8 cf[4], bfr[4];
#pragma unroll
      for (int mi = 0; mi < 4; ++mi)
        cf[mi] = *(const short8*)&Cc[((size_t)(b * SS + s0 + w * 64 + mi * 16 + lr)) * NST + ks * 32 + lhi * 8];
#pragma unroll
      for (int ni = 0; ni < 4; ++ni)
        bfr[ni] = *(const short8*)&Bc[((size_t)(b * SS + s0 + st * 64 + ni * 16 + lr)) * NST + ks * 32 + lhi * 8];
#pragma unroll
      for (int mi = 0; mi < 4; ++mi)
#pragma unroll
        for (int ni = 0; ni < 4; ++ni)
          G[mi][ni] = mfma16(cf[mi], bfr[ni], G[mi][ni]);
    }
#pragma unroll
    for (int mi = 0; mi < 4; ++mi)
#pragma unroll
      for (int ni = 0; ni < 4; ++ni) {
        int sloc = st * 64 + ni * 16 + lr;
        float ds = dtv_s[sloc];
#pragma unroll
        for (int j = 0; j < 4; ++j) {
          int l = w * 64 + mi * 16 + lhi * 4 + j;
          float v = (sloc <= l) ? G[mi][ni][j] * __expf(cumA_s[l] - cumA_s[sloc]) * ds : 0.f;
          Mw[(mi * 16 + lhi * 4 + j) * 72 + ni * 16 + lr] = f2bf(v);
        }
      }
#pragma unroll
    for (int kh = 0; kh < 2; ++kh) {
      short8 xf[4];
#pragma unroll
      for (int ni = 0; ni < 4; ++ni)
        xf[ni] = *(const short8*)&Xt[((size_t)bh * PP + ni * 16 + lr) * SS + s0 + st * 64 + kh * 32 + lhi * 8];
#pragma unroll
      for (int mi = 0; mi < 4; ++mi) {
        short8 mf = *(const short8*)&Mw[(mi * 16 + lr) * 72 + kh * 32 + lhi * 8];
#pragma unroll
        for (int ni = 0; ni < 4; ++ni)
          Yacc[mi][ni] = mfma16(mf, xf[ni], Yacc[mi][ni]);
      }
    }
  }
  // D residual folded in here: Yacc += D[h] * x[l][p]
  const float Dh = Dv[h];
#pragma unroll
  for (int mi = 0; mi < 4; ++mi)
#pragma unroll
    for (int ni = 0; ni < 4; ++ni)
#pragma unroll
      for (int j = 0; j < 4; ++j) {
        int l = w * 64 + mi * 16 + lhi * 4 + j;
        int p = ni * 16 + lr;
        float xv = bf2f(X_lp[((size_t)bh * SS + s0 + l) * PP + p]);
        ybb[((size_t)(b * SS + s0 + l)) * INTER + h * PP + p] =
            f2bf(Yacc[mi][ni][j] + Dh * xv);
      }
  f32x4 Sacc[4][2] = {};
  for (int ks = 0; ks < 8; ++ks) {
    if (cumA_s[LCC - 1] - cumA_s[ks * 32 + 31] < -30.f) continue;
    f32x4 w0 = *(const f32x4*)&w_s[ks * 32 + lhi * 8];
    f32x4 w1 = *(const f32x4*)&w_s[ks * 32 + lhi * 8 + 4];
    short8 bfr[2];
#pragma unroll
    for (int nj = 0; nj < 2; ++nj) {
      short8 br = *(const short8*)&Btc[((size_t)b * NST + w * 32 + nj * 16 + lr) * SS + s0 + ks * 32 + lhi * 8];
      short8 bs;
      bs[0] = (short)f2bf(bf2f((u16)br[0]) * w0[0]);
      bs[1] = (short)f2bf(bf2f((u16)br[1]) * w0[1]);
      bs[2] = (short)f2bf(bf2f((u16)br[2]) * w0[2]);
      bs[3] = (short)f2bf(bf2f((u16)br[3]) * w0[3]);
      bs[4] = (short)f2bf(bf2f((u16)br[4]) * w1[0]);
      bs[5] = (short)f2bf(bf2f((u16)br[5]) * w1[1]);
      bs[6] = (short)f2bf(bf2f((u16)br[6]) * w1[2]);
      bs[7] = (short)f2bf(bf2f((u16)br[7]) * w1[3]);
      bfr[nj] = bs;
    }
#pragma unroll
    for (int mi = 0; mi < 4; ++mi) {
      short8 af = *(const short8*)&Xt[((size_t)bh * PP + mi * 16 + lr) * SS + s0 + ks * 32 + lhi * 8];
#pragma unroll
      for (int nj = 0; nj < 2; ++nj)
        Sacc[mi][nj] = mfma16(af, bfr[nj], Sacc[mi][nj]);
    }
  }
#pragma unroll
  for (int mi = 0; mi < 4; ++mi)
#pragma unroll
    for (int nj = 0; nj < 2; ++nj)
#pragma unroll
      for (int j = 0; j < 4; ++j) {
        int p = mi * 16 + lhi * 4 + j;
        int n = w * 32 + nj * 16 + lr;
        statesb[((((size_t)b * NC + c) * HH + h) * PP + p) * NST + n] = f2bf(Sacc[mi][nj][j]);
      }
}

// ---------------- inter-chunk recurrence (IN PLACE: states -> prev) ------------
__global__ void reck(u16* __restrict__ statesb, const float* __restrict__ cumA) {
  int idx = blockIdx.x * 256 + threadIdx.x;  // < BB*HH*PP*NST
  int n = idx & 127, p = (idx >> 7) & 63, bh = idx >> 13;
  int b = bh >> 6, h = bh & 63;
  float prev = 0.f;
#pragma unroll
  for (int c2 = 0; c2 < NC; ++c2) {
    size_t si = ((((size_t)b * NC + c2) * HH + h) * PP + p) * NST + n;
    float s = bf2f(statesb[si]);           // read BEFORE overwrite
    statesb[si] = f2bf(prev);
    float tot = cumA[(size_t)bh * SS + c2 * LCC + (LCC - 1)];
    prev = prev * __expf(tot) + s;
  }
}

// ---------------- SSD pass 2: Y_off only (dead waves exit; live RMW) -----------
__global__ __launch_bounds__(256) void ssd2(
    const u16* __restrict__ Cc, const u16* __restrict__ prevb,
    const float* __restrict__ cumA, u16* __restrict__ ybb) {
  const int h = blockIdx.x, c = blockIdx.y, b = blockIdx.z;
  const int bh = b * HH + h, s0 = c * LCC;
  const int t = threadIdx.x, w = t >> 6, lane = t & 63, lr = lane & 15, lhi = lane >> 4;
  __shared__ float cumA_s[LCC];
  cumA_s[t] = cumA[(size_t)bh * SS + s0 + t];
  __syncthreads();
  if (cumA_s[w * 64] <= -30.f) return;
  f32x4 acc[4][4] = {};
  const size_t stbase = (((size_t)b * NC + c) * HH + h) * PP;
#pragma unroll
  for (int ks = 0; ks < 4; ++ks) {
    short8 sf[4];
#pragma unroll
    for (int pj = 0; pj < 4; ++pj)
      sf[pj] = *(const short8*)&prevb[(stbase + pj * 16 + lr) * NST + ks * 32 + lhi * 8];
#pragma unroll
    for (int mi = 0; mi < 4; ++mi) {
      short8 cf = *(const short8*)&Cc[((size_t)(b * SS + s0 + w * 64 + mi * 16 + lr)) * NST + ks * 32 + lhi * 8];
#pragma unroll
      for (int pj = 0; pj < 4; ++pj)
        acc[mi][pj] = mfma16(cf, sf[pj], acc[mi][pj]);
    }
  }
#pragma unroll
  for (int mi = 0; mi < 4; ++mi)
#pragma unroll
    for (int pj = 0; pj < 4; ++pj)
#pragma unroll
      for (int j = 0; j < 4; ++j) {
        int l = w * 64 + mi * 16 + lhi * 4 + j;
        int p = pj * 16 + lr;
        size_t yi = ((size_t)(b * SS + s0 + l)) * INTER + h * PP + p;
        float cur = bf2f(ybb[yi]);
        ybb[yi] = f2bf(cur + acc[mi][pj][j] * __expf(cumA_s[l]));
      }
}

// ---------------- gate (SiLU) + RMSNorm -> bf16 --------------------------------
__global__ __launch_bounds__(256) void gatenorm(
    const u16* __restrict__ ybb, const u16* __restrict__ gateb,
    const float* __restrict__ nw, u16* __restrict__ xgn) {
  const int r = blockIdx.x, t = threadIdx.x;
  const int w = t >> 6, lane = t & 63;
  float xg[16];
  float s2 = 0.f;
#pragma unroll
  for (int i = 0; i < 2; ++i) {
    int col = (i * 256 + t) * 8;
    short8 yv = *(const short8*)&ybb[(size_t)r * INTER + col];
    short8 gv = *(const short8*)&gateb[(size_t)r * INTER + col];
#pragma unroll
    for (int j = 0; j < 8; ++j) {
      float g = bf2f((u16)gv[j]);
      float o = bf2f((u16)yv[j]) * g * sigm(g);
      xg[i * 8 + j] = o;
      s2 += o * o;
    }
  }
#pragma unroll
  for (int off = 32; off > 0; off >>= 1) s2 += __shfl_down(s2, off);
  __shared__ float red[4];
  if (lane == 0) red[w] = s2;
  __syncthreads();
  float rstd = rsqrtf((red[0] + red[1] + red[2] + red[3]) * (1.f / INTER) + 1e-5f);
#pragma unroll
  for (int i = 0; i < 2; ++i) {
    int col = (i * 256 + t) * 8;
    float4 n0 = *(const float4*)&nw[col];
    float4 n1 = *(const float4*)&nw[col + 4];
    short8 o;
    o[0] = (short)f2bf(xg[i * 8 + 0] * rstd * n0.x);
    o[1] = (short)f2bf(xg[i * 8 + 1] * rstd * n0.y);
    o[2] = (short)f2bf(xg[i * 8 + 2] * rstd * n0.z);
    o[3] = (short)f2bf(xg[i * 8 + 3] * rstd * n0.w);
    o[4] = (short)f2bf(xg[i * 8 + 4] * rstd * n1.x);
    o[5] = (short)f2bf(xg[i * 8 + 5] * rstd * n1.y);
    o[6] = (short)f2bf(xg[i * 8 + 6] * rstd * n1.z);
    o[7] = (short)f2bf(xg[i * 8 + 7] * rstd * n1.w);
    *(short8*)&xgn[(size_t)r * INTER + col] = o;
  }
}

// ---------------- launch -------------------------------------------------------
extern "C" void kernel_launch(void* const* d_in, const int* in_sizes, int n_in,
                              void* d_out, int out_size, void* d_ws, size_t ws_size,
                              hipStream_t stream) {
  const float* hs   = (const float*)d_in[0];
  const float* w1   = (const float*)d_in[1];
  const float* b1   = (const float*)d_in[2];
  const float* cw   = (const float*)d_in[3];
  const float* dtb  = (const float*)d_in[4];
  const float* alog = (const float*)d_in[5];
  const float* Dv   = (const float*)d_in[6];
  const float* nw   = (const float*)d_in[7];
  const float* w2   = (const float*)d_in[8];
  const float* b2   = (const float*)d_in[9];
  float* out = (float*)d_out;

  char* ws = (char*)d_ws;
  size_t off = 0;
  auto alloc = [&](size_t bytes) -> char* {
    char* p = ws + off;
    off += (bytes + 255) & ~(size_t)255;
    return p;
  };
  // region A: W1t (35.1MB) -> Xt after GEMM1 -> Ppart (fp32 33.5MB) after ssd2
  char* regA = alloc((size_t)NPAD1 * HID * 2);
  u16*   W1t   = (u16*)regA;
  u16*   Xt    = (u16*)regA;
  float* Ppart = (float*)regA;
  // region B: gate (bf16) [GEMM1 .. gatenorm]
  u16* gateb = (u16*)alloc((size_t)MR * INTER * 2);
  // region C: hbc (35.7MB) -> y bf16 (33.6MB) after conv
  char* regC = alloc((size_t)MR * CONVD * 2);
  u16* hbcb = (u16*)regC;
  u16* ybb  = (u16*)regC;
  // region D: X_lp -> xgn after ssd2
  char* regD = alloc((size_t)BB * HH * SS * PP * 2);
  u16* X_lp = (u16*)regD;
  u16* xgn  = (u16*)regD;
  // region E: states bf16 (in-place -> prev) -> W2t after ssd2
  char* regE = alloc((size_t)BB * NC * HH * PP * NST * 2);
  u16* statesb = (u16*)regE;
  u16* W2t     = (u16*)regE;
  // small buffers
  u16*   hs16  = (u16*)alloc((size_t)MR * HID * 2);
  u16*   dtsec = (u16*)alloc((size_t)MR * HH * 2);
  u16*   Bc    = (u16*)alloc((size_t)BB * SS * NST * 2);
  u16*   Cc    = (u16*)alloc((size_t)BB * SS * NST * 2);
  u16*   Btc   = (u16*)alloc((size_t)BB * NST * SS * 2);
  float* dtv   = (float*)alloc((size_t)BB * HH * SS * 4);
  float* cumA  = (float*)alloc((size_t)BB * HH * SS * 4);

  if (off > ws_size) return;  // graceful fail -> diagnostic absmax

  // hs fp32 -> bf16
  f32_to_bf16<<<(MR * HID) / (256 * 8), 256, 0, stream>>>(hs, hs16);
  // W1 transpose (vectorized)
  transpose_w64<<<dim3(NPAD1 / 64, HID / 64), 256, 0, stream>>>(w1, W1t, HID, PROJD);
  // GEMM1: split epilogue -> gateb / hbcb / dtsec  (grid 67*32 = 2144, %8==0)
  gemm_bt1<<<67 * 32, 256, 0, stream>>>(hs16, W1t, b1, gateb, hbcb, dtsec,
                                        PROJD, HID, 67);
  // conv X-part with fused transpose dual-write (Xt overwrites W1t: dead)
  conv_x<<<dim3(SS / 64, HH, BB), 256, 0, stream>>>(hbcb, cw, X_lp, Xt);
  // conv B/C channels (256 channels = 32 chunks)
  conv_bc<<<(BB * SS * 32) / 256, 256, 0, stream>>>(hbcb, cw, Bc, Cc);
  // fused dt softplus + per-chunk cumsum
  dt_cumsum<<<BB * HH, 256, 0, stream>>>(dtsec, dtb, alog, dtv, cumA);
  // B transpose for states-pass fragments (4 MB)
  transpose_bf16<<<dim3(NST / 32, SS / 32, BB), 256, 0, stream>>>(Bc, Btc, SS, NST);
  // SSD pass 1: Y_diag + D residual + chunk states (ybb overwrites hbcb)
  ssd1<<<dim3(HH, NC, BB), 256, 0, stream>>>(Cc, Bc, Btc, Xt, X_lp, Dv,
                                             cumA, dtv, ybb, statesb);
  // inter-chunk recurrence, in place
  reck<<<(BB * HH * PP * NST) / 256, 256, 0, stream>>>(statesb, cumA);
  // SSD pass 2: Y_off only (live waves RMW)
  ssd2<<<dim3(HH, NC, BB), 256, 0, stream>>>(Cc, statesb, cumA, ybb);
  // W2 transpose into region E (states dead after ssd2)
  transpose_w64<<<dim3(HID / 64, INTER / 64), 256, 0, stream>>>(w2, W2t, INTER, HID);
  // gate + RMSNorm (xgn overwrites X_lp: dead after ssd2)
  gatenorm<<<MR, 256, 0, stream>>>(ybb, gateb, nw, xgn);
  // GEMM2 split-K x2 (Ppart overwrites Xt region: dead after ssd2)
  gemm2_sk<<<1024, 256, 0, stream>>>(xgn, W2t, b2, out, Ppart);
  // fixup: out += Ppart
  addbuf<<<(MR * HID) / (256 * 4), 256, 0, stream>>>(out, Ppart);
}

// Round 14
// 497.606 us; speedup vs baseline: 1.0217x; 1.0217x over previous
//
#include <hip/hip_runtime.h>

// ---------------- dims ----------------
constexpr int HH    = 64;     // heads
constexpr int PP    = 64;     // head dim
constexpr int HID   = 2048;
constexpr int NST   = 128;    // state dim
constexpr int LCC   = 256;    // chunk len
constexpr int INTER = 4096;
constexpr int CONVD = 4352;
constexpr int PROJD = 8512;
constexpr int BB    = 4;
constexpr int SS    = 1024;
constexpr int NC    = 4;      // chunks
constexpr int MR    = BB * SS;      // 4096 rows
constexpr int NPAD1 = 8704;         // PROJD padded to 256 (GEMM1 256^2 tiles: 34)

typedef unsigned short u16;
typedef __bf16 bf16x8_t __attribute__((ext_vector_type(8)));
typedef short short8 __attribute__((ext_vector_type(8)));
typedef float f32x4 __attribute__((ext_vector_type(4)));
typedef u16 u16x4 __attribute__((ext_vector_type(4)));

__device__ __forceinline__ float bf2f(u16 u) {
  union { unsigned int i; float f; } v; v.i = ((unsigned int)u) << 16; return v.f;
}
__device__ __forceinline__ u16 f2bf(float f) {
  union { float f; unsigned int i; } v; v.f = f;
  unsigned int r = v.i + 0x7FFFu + ((v.i >> 16) & 1u);
  return (u16)(r >> 16);
}
__device__ __forceinline__ f32x4 mfma16(short8 a, short8 b, f32x4 c) {
  union U { short8 s; bf16x8_t b; };
  U ua; ua.s = a; U ub; ub.s = b;
  return __builtin_amdgcn_mfma_f32_16x16x32_bf16(ua.b, ub.b, c, 0, 0, 0);
}
__device__ __forceinline__ float sigm(float x) { return 1.f / (1.f + __expf(-x)); }
__device__ __forceinline__ void gload16(const u16* g, u16* l) {
  __builtin_amdgcn_global_load_lds(
      (const __attribute__((address_space(1))) void*)g,
      (__attribute__((address_space(3))) void*)l, 16, 0, 0);
}

// ---------------- fp32 -> bf16 convert (hs) ------------------------------------
__global__ void f32_to_bf16(const float* __restrict__ in, u16* __restrict__ out) {
  int i = (blockIdx.x * 256 + threadIdx.x) * 8;
  float4 a = *(const float4*)&in[i];
  float4 b = *(const float4*)&in[i + 4];
  short8 v;
  v[0] = (short)f2bf(a.x); v[1] = (short)f2bf(a.y);
  v[2] = (short)f2bf(a.z); v[3] = (short)f2bf(a.w);
  v[4] = (short)f2bf(b.x); v[5] = (short)f2bf(b.y);
  v[6] = (short)f2bf(b.z); v[7] = (short)f2bf(b.w);
  *(short8*)&out[i] = v;
}

// ---------------- vectorized weight transpose: in [K][N] f32 -> out [Npad][K] bf16
__global__ __launch_bounds__(256) void transpose_w64(
    const float* __restrict__ in, u16* __restrict__ out, int K_, int N_) {
  const int n0 = blockIdx.x * 64, k0 = blockIdx.y * 64;
  const int t = threadIdx.x;
  __shared__ u16 tile[64][72];   // [n][k]
#pragma unroll
  for (int i = 0; i < 4; ++i) {
    int idx = i * 256 + t;            // 0..1023
    int kk = idx >> 4;                // 0..63
    int nc = (idx & 15) * 4;          // 0..60
    int n = n0 + nc;
    float4 v = make_float4(0.f, 0.f, 0.f, 0.f);
    if (n + 3 < N_) v = *(const float4*)&in[(size_t)(k0 + kk) * N_ + n];
    tile[nc + 0][kk] = f2bf(v.x);
    tile[nc + 1][kk] = f2bf(v.y);
    tile[nc + 2][kk] = f2bf(v.z);
    tile[nc + 3][kk] = f2bf(v.w);
  }
  __syncthreads();
#pragma unroll
  for (int i = 0; i < 2; ++i) {
    int idx = i * 256 + t;            // 0..511
    int nn = idx >> 3;                // 0..63
    int kc = (idx & 7) * 8;
    *(short8*)&out[(size_t)(n0 + nn) * K_ + k0 + kc] =
        *(const short8*)&tile[nn][kc];
  }
}

// ---------------- generic bf16 transpose (B only): in [R][C] -> out [C][R] -----
__global__ void transpose_bf16(const u16* __restrict__ in, u16* __restrict__ out,
                               int R, int C) {
  int bt = blockIdx.z;
  const u16* ip = in + (size_t)bt * R * C;
  u16* op = out + (size_t)bt * R * C;
  __shared__ u16 tile[32][33];
  int r0 = blockIdx.y * 32, c0 = blockIdx.x * 32, t = threadIdx.x;
#pragma unroll
  for (int i = 0; i < 4; ++i) {
    int flat = i * 256 + t; int rr = flat >> 5, cc = flat & 31;
    tile[rr][cc] = ip[(size_t)(r0 + rr) * C + c0 + cc];
  }
  __syncthreads();
#pragma unroll
  for (int i = 0; i < 4; ++i) {
    int flat = i * 256 + t; int cc = flat >> 5, rr = flat & 31;
    op[(size_t)(c0 + cc) * R + r0 + rr] = tile[rr][cc];
  }
}

// ================= GEMM1: 256x256, 8 waves, K-slice 8-phase, counted vmcnt =====
// LDS: A[2buf][2ks][256][32] @0 ; B same @32768 u16. Slice = 2 gloads/thread.
// Phases P1/P2 use ks0, P3/P4 use ks1 -> slice staged >=3 phases before use.
// vmcnt(4) at P2-end & P4-end only (never 0 in loop).
__global__ __launch_bounds__(512, 1) void gemm1_8ph(
    const u16* __restrict__ A, const u16* __restrict__ Bt,
    const float* __restrict__ bias, u16* __restrict__ gateb,
    u16* __restrict__ hbcb, u16* __restrict__ dtsec,
    int Nreal, int K, int gx) {
  extern __shared__ u16 smem[];
  const int nwg = gridDim.x, bid = blockIdx.x;
  const int q = nwg >> 3;                         // bijective (nwg%8==0)
  const int swz = (bid & 7) * q + (bid >> 3);
  const int bx = swz % gx, by = swz / gx;
  const int m0 = by * 256, n0 = bx * 256;
  const int t = threadIdx.x;
  const int w = t >> 6, lane = t & 63, lr = lane & 15, lhi = lane >> 4;
  const int wr = w >> 2, wc = w & 3;              // 2M x 4N waves
  const int NT = K >> 6;
  // stage-side addressing: thread t covers row (t>>2) (+i*128), 16B chunk (t&3),
  // global col pre-swizzled by ((row>>1)&3) = ((t>>3)&3)
  const int srow = t >> 2;
  const int swcol = (((t & 3) ^ ((t >> 3) & 3)) << 3);
  const u16* gA = A + (size_t)(m0 + srow) * K + swcol;
  const u16* gB = Bt + (size_t)(n0 + srow) * K + swcol;
  const int rsw = ((lr >> 1) & 3);                // read-side XOR (chunk)

#define SLC_A(bb, ks) (smem + (bb)*16384 + (ks)*8192)
#define SLC_B(bb, ks) (smem + 32768 + (bb)*16384 + (ks)*8192)
#define STAGE_A(kt, ks, bb)                                                    \
  { const u16* s_ = gA + (size_t)(kt)*64 + (ks)*32;                            \
    u16* d_ = SLC_A(bb, ks) + w * 512;                                         \
    gload16(s_, d_);                                                           \
    gload16(s_ + (size_t)128 * K, d_ + 4096); }
#define STAGE_B(kt, ks, bb)                                                    \
  { const u16* s_ = gB + (size_t)(kt)*64 + (ks)*32;                            \
    u16* d_ = SLC_B(bb, ks) + w * 512;                                         \
    gload16(s_, d_);                                                           \
    gload16(s_ + (size_t)128 * K, d_ + 4096); }
#define LDA(bb, ks, mi) (*(const short8*)(SLC_A(bb, ks) +                      \
    (wr * 128 + (mi)*16 + lr) * 32 + (((lhi) ^ rsw) << 3)))
#define LDB(bb, ks, ni) (*(const short8*)(SLC_B(bb, ks) +                      \
    (wc * 64 + (ni)*16 + lr) * 32 + (((lhi) ^ rsw) << 3)))
#define PH_TOP()                                                               \
  __builtin_amdgcn_s_barrier();                                                \
  asm volatile("s_waitcnt lgkmcnt(0)" ::: "memory");                           \
  __builtin_amdgcn_sched_barrier(0);                                           \
  __builtin_amdgcn_s_setprio(1);
#define PH_BOT()                                                               \
  __builtin_amdgcn_s_setprio(0);                                               \
  __builtin_amdgcn_sched_barrier(0);                                           \
  __builtin_amdgcn_s_barrier();
#define PH_BOT_W()                                                             \
  __builtin_amdgcn_s_setprio(0);                                               \
  __builtin_amdgcn_sched_barrier(0);                                           \
  asm volatile("s_waitcnt vmcnt(4)" ::: "memory");                             \
  __builtin_amdgcn_s_barrier();
#define MFMA2(a, b)                                                            \
  _Pragma("unroll") for (int mi = 0; mi < 8; ++mi) {                           \
    acc[mi][a] = mfma16(af[mi], bf[a], acc[mi][a]);                            \
    acc[mi][b] = mfma16(af[mi], bf[b], acc[mi][b]);                            \
  }

  // prologue: tile 0 fully staged, one-time full drain
  STAGE_A(0, 0, 0); STAGE_B(0, 0, 0); STAGE_A(0, 1, 0); STAGE_B(0, 1, 0);
  asm volatile("s_waitcnt vmcnt(0)" ::: "memory");
  __builtin_amdgcn_s_barrier();

  f32x4 acc[8][4] = {};
  short8 af[8], bf[4];
#pragma unroll 1
  for (int T = 0; T < NT; ++T) {
    const int bb = T & 1, nb = bb ^ 1;
    const int ktn = (T + 1 < NT) ? T + 1 : T;   // tail re-stage: benign
    // P1: ks0, ni{0,1}; stage A-ks0(T+1)
#pragma unroll
    for (int mi = 0; mi < 8; ++mi) af[mi] = LDA(bb, 0, mi);
    bf[0] = LDB(bb, 0, 0); bf[1] = LDB(bb, 0, 1);
    STAGE_A(ktn, 0, nb);
    __builtin_amdgcn_sched_barrier(0);
    PH_TOP(); MFMA2(0, 1); PH_BOT();
    // P2: ks0, ni{2,3}; stage B-ks0(T+1); wait A1/B1(T) resident
    bf[2] = LDB(bb, 0, 2); bf[3] = LDB(bb, 0, 3);
    STAGE_B(ktn, 0, nb);
    __builtin_amdgcn_sched_barrier(0);
    PH_TOP(); MFMA2(2, 3); PH_BOT_W();
    // P3: ks1, ni{0,1}; stage A-ks1(T+1)
#pragma unroll
    for (int mi = 0; mi < 8; ++mi) af[mi] = LDA(bb, 1, mi);
    bf[0] = LDB(bb, 1, 0); bf[1] = LDB(bb, 1, 1);
    STAGE_A(ktn, 1, nb);
    __builtin_amdgcn_sched_barrier(0);
    PH_TOP(); MFMA2(0, 1); PH_BOT();
    // P4: ks1, ni{2,3}; stage B-ks1(T+1); wait A0/B0(T+1) resident
    bf[2] = LDB(bb, 1, 2); bf[3] = LDB(bb, 1, 3);
    STAGE_B(ktn, 1, nb);
    __builtin_amdgcn_sched_barrier(0);
    PH_TOP(); MFMA2(2, 3); PH_BOT_W();
  }
#undef SLC_A
#undef SLC_B
#undef STAGE_A
#undef STAGE_B
#undef LDA
#undef LDB
#undef PH_TOP
#undef PH_BOT
#undef PH_BOT_W
#undef MFMA2

#pragma unroll
  for (int ni = 0; ni < 4; ++ni) {
    int col = n0 + wc * 64 + ni * 16 + lr;
    if (col >= Nreal) continue;
    float bv = bias[col];
#pragma unroll
    for (int mi = 0; mi < 8; ++mi)
#pragma unroll
      for (int j = 0; j < 4; ++j) {
        int row = m0 + wr * 128 + mi * 16 + lhi * 4 + j;
        float v = acc[mi][ni][j] + bv;
        u16 o = f2bf(v);
        if (col < INTER)              gateb[(size_t)row * INTER + col] = o;
        else if (col < INTER + CONVD) hbcb[(size_t)row * CONVD + (col - INTER)] = o;
        else                          dtsec[(size_t)row * HH + (col - INTER - CONVD)] = o;
      }
  }
}

// ================= GEMM2 (proven R4): out fp32 =================================
__global__ __launch_bounds__(256) void gemm2_r4(
    const u16* __restrict__ A, const u16* __restrict__ Bt,
    const float* __restrict__ bias, float* __restrict__ Cp,
    int Nreal, int K, int gx) {
  __shared__ __align__(16) u16 As[128 * 64];
  __shared__ __align__(16) u16 Bs[128 * 64];
  const int nwg = gridDim.x, bid = blockIdx.x;
  const int q = nwg >> 3;
  const int swz = (bid & 7) * q + (bid >> 3);
  const int bx = swz % gx, by = swz / gx;
  const int m0 = by * 128, n0 = bx * 128;
  const int t = threadIdx.x;
  const int w = t >> 6, lane = t & 63, lr = lane & 15, lhi = lane >> 4;
  const int wr = (w >> 1) * 64, wc = (w & 1) * 64;
  const int srow = t >> 3;
  const int sw_scol = (((t & 7) ^ ((t >> 3) & 7)) << 3);
  const u16* ga = A + (size_t)(m0 + srow) * K + sw_scol;
  const u16* gb = Bt + (size_t)(n0 + srow) * K + sw_scol;
  u16* la = As + w * 512;
  u16* lb = Bs + w * 512;
  const int swz_rd = (lr & 7) << 3;
  f32x4 acc[4][4] = {};
  for (int k0 = 0; k0 < K; k0 += 64) {
    __syncthreads();
#pragma unroll
    for (int j = 0; j < 4; ++j) {
      gload16(ga + (size_t)(j * 32) * K + k0, la + j * 2048);
      gload16(gb + (size_t)(j * 32) * K + k0, lb + j * 2048);
    }
    __syncthreads();
#pragma unroll
    for (int ks = 0; ks < 2; ++ks) {
      const int cs = (ks * 32 + lhi * 8) ^ swz_rd;
      short8 af[4], bfv[4];
#pragma unroll
      for (int mi = 0; mi < 4; ++mi)
        af[mi] = *(const short8*)&As[(wr + mi * 16 + lr) * 64 + cs];
#pragma unroll
      for (int ni = 0; ni < 4; ++ni)
        bfv[ni] = *(const short8*)&Bs[(wc + ni * 16 + lr) * 64 + cs];
#pragma unroll
      for (int mi = 0; mi < 4; ++mi)
#pragma unroll
        for (int ni = 0; ni < 4; ++ni)
          acc[mi][ni] = mfma16(af[mi], bfv[ni], acc[mi][ni]);
    }
  }
#pragma unroll
  for (int ni = 0; ni < 4; ++ni) {
    int col = n0 + wc + ni * 16 + lr;
    if (col >= Nreal) continue;
    float bv = bias[col];
#pragma unroll
    for (int mi = 0; mi < 4; ++mi)
#pragma unroll
      for (int j = 0; j < 4; ++j) {
        int row = m0 + wr + mi * 16 + lhi * 4 + j;
        Cp[(size_t)row * Nreal + col] = acc[mi][ni][j] + bv;
      }
  }
}

// ---------------- conv1d X-part + SiLU, fused transpose dual-write -------------
__global__ __launch_bounds__(256) void conv_x(
    const u16* __restrict__ hbcb, const float* __restrict__ convw,
    u16* __restrict__ X_lp, u16* __restrict__ Xt) {
  const int st = blockIdx.x, h = blockIdx.y, b = blockIdx.z;
  const int s0 = st * 64;
  const int t = threadIdx.x;
  const int bh = b * HH + h;
  __shared__ u16 tile[64][72];   // [s][p]
#pragma unroll
  for (int i = 0; i < 2; ++i) {
    int idx = i * 256 + t;       // 0..511
    int s = idx >> 3;            // 0..63
    int pc = (idx & 7) * 8;
    short8 v[4];
#pragma unroll
    for (int k = 0; k < 4; ++k) {
      int ss = s0 + s - 3 + k;
      if (ss >= 0)
        v[k] = *(const short8*)&hbcb[(size_t)(b * SS + ss) * CONVD + h * 64 + pc];
      else
        v[k] = short8{0, 0, 0, 0, 0, 0, 0, 0};
    }
    short8 o;
#pragma unroll
    for (int j = 0; j < 8; ++j) {
      float4 wj = *(const float4*)&convw[(h * 64 + pc + j) * 4];
      float a = bf2f((u16)v[0][j]) * wj.x + bf2f((u16)v[1][j]) * wj.y +
                bf2f((u16)v[2][j]) * wj.z + bf2f((u16)v[3][j]) * wj.w;
      o[j] = (short)f2bf(a * sigm(a));
    }
    *(short8*)&X_lp[((size_t)bh * SS + s0 + s) * PP + pc] = o;
    *(short8*)&tile[s][pc] = o;
  }
  __syncthreads();
#pragma unroll
  for (int i = 0; i < 2; ++i) {
    int idx = i * 256 + t;
    int p = idx >> 3;            // 0..63
    int sc = (idx & 7) * 8;
    short8 o;
#pragma unroll
    for (int j = 0; j < 8; ++j) o[j] = (short)tile[sc + j][p];
    *(short8*)&Xt[((size_t)bh * PP + p) * SS + s0 + sc] = o;
  }
}

// ---------------- conv1d B/C channels (256 ch = 32 chunks of 8) + SiLU ---------
__global__ __launch_bounds__(256) void conv_bc(
    const u16* __restrict__ hbcb, const float* __restrict__ convw,
    u16* __restrict__ Bc, u16* __restrict__ Cc) {
  int idx = blockIdx.x * 256 + threadIdx.x;   // < BB*SS*32
  int c8 = idx & 31;
  int rest = idx >> 5;
  int s = rest & (SS - 1);
  int b = rest >> 10;
  int ch = INTER + c8 * 8;                    // [4096, 4352)
  short8 v[4];
#pragma unroll
  for (int k = 0; k < 4; ++k) {
    int ss = s - 3 + k;
    if (ss >= 0) v[k] = *(const short8*)&hbcb[(size_t)(b * SS + ss) * CONVD + ch];
    else         v[k] = short8{0, 0, 0, 0, 0, 0, 0, 0};
  }
  short8 o;
#pragma unroll
  for (int j = 0; j < 8; ++j) {
    float4 wj = *(const float4*)&convw[(ch + j) * 4];
    float a = bf2f((u16)v[0][j]) * wj.x + bf2f((u16)v[1][j]) * wj.y +
              bf2f((u16)v[2][j]) * wj.z + bf2f((u16)v[3][j]) * wj.w;
    o[j] = (short)f2bf(a * sigm(a));
  }
  if (ch < INTER + NST)
    *(short8*)&Bc[((size_t)(b * SS + s)) * NST + (ch - INTER)] = o;
  else
    *(short8*)&Cc[((size_t)(b * SS + s)) * NST + (ch - INTER - NST)] = o;
}

// ---------------- fused dt softplus + per-chunk cumsum (wave scan) -------------
__global__ __launch_bounds__(256) void dt_cumsum(
    const u16* __restrict__ dtsec, const float* __restrict__ dtb,
    const float* __restrict__ alog, float* __restrict__ dtv,
    float* __restrict__ cumA) {
  const int bh = blockIdx.x;
  const int b = bh >> 6, h = bh & 63;
  const int t = threadIdx.x, w = t >> 6, lane = t & 63;
  const float na = -__expf(alog[h]);
  const float db = dtb[h];
  size_t base = (size_t)bh * SS + w * LCC;
  float d[4];
#pragma unroll
  for (int j = 0; j < 4; ++j) {
    int s = w * LCC + lane * 4 + j;
    float x = bf2f(dtsec[(size_t)(b * SS + s) * HH + h]) + db;
    d[j] = (x > 20.f) ? x : log1pf(__expf(x));
  }
  *(float4*)&dtv[base + lane * 4] = make_float4(d[0], d[1], d[2], d[3]);
  float a0 = na * d[0];
  float s1 = a0 + na * d[1];
  float s2 = s1 + na * d[2];
  float tot = s2 + na * d[3];
  float run = tot;
#pragma unroll
  for (int off = 1; off < 64; off <<= 1) {
    float u = __shfl_up(run, off);
    if (lane >= off) run += u;
  }
  float excl = run - tot;
  float4 o; o.x = excl + a0; o.y = excl + s1; o.z = excl + s2; o.w = excl + tot;
  *(float4*)&cumA[base + lane * 4] = o;
}

// ---------------- SSD pass 1: Y_diag + D residual + chunk states (decay-skip) --
__global__ __launch_bounds__(256) void ssd1(
    const u16* __restrict__ Cc, const u16* __restrict__ Bc,
    const u16* __restrict__ Btc, const u16* __restrict__ Xt,
    const u16* __restrict__ X_lp, const float* __restrict__ Dv,
    const float* __restrict__ cumA, const float* __restrict__ dtv,
    u16* __restrict__ ybb, u16* __restrict__ statesb) {
  const int h = blockIdx.x, c = blockIdx.y, b = blockIdx.z;
  const int bh = b * HH + h, s0 = c * LCC;
  const int t = threadIdx.x, w = t >> 6, lane = t & 63, lr = lane & 15, lhi = lane >> 4;
  __shared__ float cumA_s[LCC], dtv_s[LCC], w_s[LCC];
  __shared__ __align__(16) u16 Mld[4][64 * 72];
  cumA_s[t] = cumA[(size_t)bh * SS + s0 + t];
  dtv_s[t] = dtv[(size_t)bh * SS + s0 + t];
  __syncthreads();
  w_s[t] = dtv_s[t] * __expf(cumA_s[LCC - 1] - cumA_s[t]);
  __syncthreads();

  f32x4 Yacc[4][4] = {};
  u16* Mw = &Mld[w][0];
  for (int st = 0; st <= w; ++st) {
    if (st < w && (cumA_s[w * 64] - cumA_s[st * 64 + 63] < -30.f)) continue;
    f32x4 G[4][4] = {};
#pragma unroll
    for (int ks = 0; ks < 4; ++ks) {
      short8 cf[4], bfr[4];
#pragma unroll
      for (int mi = 0; mi < 4; ++mi)
        cf[mi] = *(const short8*)&Cc[((size_t)(b * SS + s0 + w * 64 + mi * 16 + lr)) * NST + ks * 32 + lhi * 8];
#pragma unroll
      for (int ni = 0; ni < 4; ++ni)
        bfr[ni] = *(const short8*)&Bc[((size_t)(b * SS + s0 + st * 64 + ni * 16 + lr)) * NST + ks * 32 + lhi * 8];
#pragma unroll
      for (int mi = 0; mi < 4; ++mi)
#pragma unroll
        for (int ni = 0; ni < 4; ++ni)
          G[mi][ni] = mfma16(cf[mi], bfr[ni], G[mi][ni]);
    }
#pragma unroll
    for (int mi = 0; mi < 4; ++mi)
#pragma unroll
      for (int ni = 0; ni < 4; ++ni) {
        int sloc = st * 64 + ni * 16 + lr;
        float ds = dtv_s[sloc];
#pragma unroll
        for (int j = 0; j < 4; ++j) {
          int l = w * 64 + mi * 16 + lhi * 4 + j;
          float v = (sloc <= l) ? G[mi][ni][j] * __expf(cumA_s[l] - cumA_s[sloc]) * ds : 0.f;
          Mw[(mi * 16 + lhi * 4 + j) * 72 + ni * 16 + lr] = f2bf(v);
        }
      }
#pragma unroll
    for (int kh = 0; kh < 2; ++kh) {
      short8 xf[4];
#pragma unroll
      for (int ni = 0; ni < 4; ++ni)
        xf[ni] = *(const short8*)&Xt[((size_t)bh * PP + ni * 16 + lr) * SS + s0 + st * 64 + kh * 32 + lhi * 8];
#pragma unroll
      for (int mi = 0; mi < 4; ++mi) {
        short8 mf = *(const short8*)&Mw[(mi * 16 + lr) * 72 + kh * 32 + lhi * 8];
#pragma unroll
        for (int ni = 0; ni < 4; ++ni)
          Yacc[mi][ni] = mfma16(mf, xf[ni], Yacc[mi][ni]);
      }
    }
  }
  const float Dh = Dv[h];
#pragma unroll
  for (int mi = 0; mi < 4; ++mi)
#pragma unroll
    for (int ni = 0; ni < 4; ++ni)
#pragma unroll
      for (int j = 0; j < 4; ++j) {
        int l = w * 64 + mi * 16 + lhi * 4 + j;
        int p = ni * 16 + lr;
        float xv = bf2f(X_lp[((size_t)bh * SS + s0 + l) * PP + p]);
        ybb[((size_t)(b * SS + s0 + l)) * INTER + h * PP + p] =
            f2bf(Yacc[mi][ni][j] + Dh * xv);
      }
  f32x4 Sacc[4][2] = {};
  for (int ks = 0; ks < 8; ++ks) {
    if (cumA_s[LCC - 1] - cumA_s[ks * 32 + 31] < -30.f) continue;
    f32x4 w0 = *(const f32x4*)&w_s[ks * 32 + lhi * 8];
    f32x4 w1 = *(const f32x4*)&w_s[ks * 32 + lhi * 8 + 4];
    short8 bfr[2];
#pragma unroll
    for (int nj = 0; nj < 2; ++nj) {
      short8 br = *(const short8*)&Btc[((size_t)b * NST + w * 32 + nj * 16 + lr) * SS + s0 + ks * 32 + lhi * 8];
      short8 bs;
      bs[0] = (short)f2bf(bf2f((u16)br[0]) * w0[0]);
      bs[1] = (short)f2bf(bf2f((u16)br[1]) * w0[1]);
      bs[2] = (short)f2bf(bf2f((u16)br[2]) * w0[2]);
      bs[3] = (short)f2bf(bf2f((u16)br[3]) * w0[3]);
      bs[4] = (short)f2bf(bf2f((u16)br[4]) * w1[0]);
      bs[5] = (short)f2bf(bf2f((u16)br[5]) * w1[1]);
      bs[6] = (short)f2bf(bf2f((u16)br[6]) * w1[2]);
      bs[7] = (short)f2bf(bf2f((u16)br[7]) * w1[3]);
      bfr[nj] = bs;
    }
#pragma unroll
    for (int mi = 0; mi < 4; ++mi) {
      short8 af = *(const short8*)&Xt[((size_t)bh * PP + mi * 16 + lr) * SS + s0 + ks * 32 + lhi * 8];
#pragma unroll
      for (int nj = 0; nj < 2; ++nj)
        Sacc[mi][nj] = mfma16(af, bfr[nj], Sacc[mi][nj]);
    }
  }
#pragma unroll
  for (int mi = 0; mi < 4; ++mi)
#pragma unroll
    for (int nj = 0; nj < 2; ++nj)
#pragma unroll
      for (int j = 0; j < 4; ++j) {
        int p = mi * 16 + lhi * 4 + j;
        int n = w * 32 + nj * 16 + lr;
        statesb[((((size_t)b * NC + c) * HH + h) * PP + p) * NST + n] = f2bf(Sacc[mi][nj][j]);
      }
}

// ---------------- inter-chunk recurrence (IN PLACE: states -> prev) ------------
__global__ void reck(u16* __restrict__ statesb, const float* __restrict__ cumA) {
  int idx = blockIdx.x * 256 + threadIdx.x;  // < BB*HH*PP*NST
  int n = idx & 127, p = (idx >> 7) & 63, bh = idx >> 13;
  int b = bh >> 6, h = bh & 63;
  float prev = 0.f;
#pragma unroll
  for (int c2 = 0; c2 < NC; ++c2) {
    size_t si = ((((size_t)b * NC + c2) * HH + h) * PP + p) * NST + n;
    float s = bf2f(statesb[si]);           // read BEFORE overwrite
    statesb[si] = f2bf(prev);
    float tot = cumA[(size_t)bh * SS + c2 * LCC + (LCC - 1)];
    prev = prev * __expf(tot) + s;
  }
}

// ---------------- SSD pass 2: Y_off only (dead waves exit; live RMW) -----------
__global__ __launch_bounds__(256) void ssd2(
    const u16* __restrict__ Cc, const u16* __restrict__ prevb,
    const float* __restrict__ cumA, u16* __restrict__ ybb) {
  const int h = blockIdx.x, c = blockIdx.y, b = blockIdx.z;
  const int bh = b * HH + h, s0 = c * LCC;
  const int t = threadIdx.x, w = t >> 6, lane = t & 63, lr = lane & 15, lhi = lane >> 4;
  __shared__ float cumA_s[LCC];
  cumA_s[t] = cumA[(size_t)bh * SS + s0 + t];
  __syncthreads();
  if (cumA_s[w * 64] <= -30.f) return;
  f32x4 acc[4][4] = {};
  const size_t stbase = (((size_t)b * NC + c) * HH + h) * PP;
#pragma unroll
  for (int ks = 0; ks < 4; ++ks) {
    short8 sf[4];
#pragma unroll
    for (int pj = 0; pj < 4; ++pj)
      sf[pj] = *(const short8*)&prevb[(stbase + pj * 16 + lr) * NST + ks * 32 + lhi * 8];
#pragma unroll
    for (int mi = 0; mi < 4; ++mi) {
      short8 cf = *(const short8*)&Cc[((size_t)(b * SS + s0 + w * 64 + mi * 16 + lr)) * NST + ks * 32 + lhi * 8];
#pragma unroll
      for (int pj = 0; pj < 4; ++pj)
        acc[mi][pj] = mfma16(cf, sf[pj], acc[mi][pj]);
    }
  }
#pragma unroll
  for (int mi = 0; mi < 4; ++mi)
#pragma unroll
    for (int pj = 0; pj < 4; ++pj)
#pragma unroll
      for (int j = 0; j < 4; ++j) {
        int l = w * 64 + mi * 16 + lhi * 4 + j;
        int p = pj * 16 + lr;
        size_t yi = ((size_t)(b * SS + s0 + l)) * INTER + h * PP + p;
        float cur = bf2f(ybb[yi]);
        ybb[yi] = f2bf(cur + acc[mi][pj][j] * __expf(cumA_s[l]));
      }
}

// ---------------- gate (SiLU) + RMSNorm -> bf16 --------------------------------
__global__ __launch_bounds__(256) void gatenorm(
    const u16* __restrict__ ybb, const u16* __restrict__ gateb,
    const float* __restrict__ nw, u16* __restrict__ xgn) {
  const int r = blockIdx.x, t = threadIdx.x;
  const int w = t >> 6, lane = t & 63;
  float xg[16];
  float s2 = 0.f;
#pragma unroll
  for (int i = 0; i < 2; ++i) {
    int col = (i * 256 + t) * 8;
    short8 yv = *(const short8*)&ybb[(size_t)r * INTER + col];
    short8 gv = *(const short8*)&gateb[(size_t)r * INTER + col];
#pragma unroll
    for (int j = 0; j < 8; ++j) {
      float g = bf2f((u16)gv[j]);
      float o = bf2f((u16)yv[j]) * g * sigm(g);
      xg[i * 8 + j] = o;
      s2 += o * o;
    }
  }
#pragma unroll
  for (int off = 32; off > 0; off >>= 1) s2 += __shfl_down(s2, off);
  __shared__ float red[4];
  if (lane == 0) red[w] = s2;
  __syncthreads();
  float rstd = rsqrtf((red[0] + red[1] + red[2] + red[3]) * (1.f / INTER) + 1e-5f);
#pragma unroll
  for (int i = 0; i < 2; ++i) {
    int col = (i * 256 + t) * 8;
    float4 n0 = *(const float4*)&nw[col];
    float4 n1 = *(const float4*)&nw[col + 4];
    short8 o;
    o[0] = (short)f2bf(xg[i * 8 + 0] * rstd * n0.x);
    o[1] = (short)f2bf(xg[i * 8 + 1] * rstd * n0.y);
    o[2] = (short)f2bf(xg[i * 8 + 2] * rstd * n0.z);
    o[3] = (short)f2bf(xg[i * 8 + 3] * rstd * n0.w);
    o[4] = (short)f2bf(xg[i * 8 + 4] * rstd * n1.x);
    o[5] = (short)f2bf(xg[i * 8 + 5] * rstd * n1.y);
    o[6] = (short)f2bf(xg[i * 8 + 6] * rstd * n1.z);
    o[7] = (short)f2bf(xg[i * 8 + 7] * rstd * n1.w);
    *(short8*)&xgn[(size_t)r * INTER + col] = o;
  }
}

// ---------------- launch -------------------------------------------------------
extern "C" void kernel_launch(void* const* d_in, const int* in_sizes, int n_in,
                              void* d_out, int out_size, void* d_ws, size_t ws_size,
                              hipStream_t stream) {
  const float* hs   = (const float*)d_in[0];
  const float* w1   = (const float*)d_in[1];
  const float* b1   = (const float*)d_in[2];
  const float* cw   = (const float*)d_in[3];
  const float* dtb  = (const float*)d_in[4];
  const float* alog = (const float*)d_in[5];
  const float* Dv   = (const float*)d_in[6];
  const float* nw   = (const float*)d_in[7];
  const float* w2   = (const float*)d_in[8];
  const float* b2   = (const float*)d_in[9];
  float* out = (float*)d_out;

  char* ws = (char*)d_ws;
  size_t off = 0;
  auto alloc = [&](size_t bytes) -> char* {
    char* p = ws + off;
    off += (bytes + 255) & ~(size_t)255;
    return p;
  };
  // region A: W1t (35.7MB, NPAD 8704) -> Xt (33.6MB) after GEMM1
  char* regA = alloc((size_t)NPAD1 * HID * 2);
  u16* W1t = (u16*)regA;
  u16* Xt  = (u16*)regA;
  // region B: gate (bf16) [GEMM1 .. gatenorm]
  u16* gateb = (u16*)alloc((size_t)MR * INTER * 2);
  // region C: hbc (35.7MB) -> y bf16 (33.6MB) after conv
  char* regC = alloc((size_t)MR * CONVD * 2);
  u16* hbcb = (u16*)regC;
  u16* ybb  = (u16*)regC;
  // region D: X_lp -> xgn after ssd2
  char* regD = alloc((size_t)BB * HH * SS * PP * 2);
  u16* X_lp = (u16*)regD;
  u16* xgn  = (u16*)regD;
  // region E: states bf16 (in-place -> prev) -> W2t after ssd2
  char* regE = alloc((size_t)BB * NC * HH * PP * NST * 2);
  u16* statesb = (u16*)regE;
  u16* W2t     = (u16*)regE;
  // small buffers
  u16*   hs16  = (u16*)alloc((size_t)MR * HID * 2);
  u16*   dtsec = (u16*)alloc((size_t)MR * HH * 2);
  u16*   Bc    = (u16*)alloc((size_t)BB * SS * NST * 2);
  u16*   Cc    = (u16*)alloc((size_t)BB * SS * NST * 2);
  u16*   Btc   = (u16*)alloc((size_t)BB * NST * SS * 2);
  float* dtv   = (float*)alloc((size_t)BB * HH * SS * 4);
  float* cumA  = (float*)alloc((size_t)BB * HH * SS * 4);

  if (off > ws_size) return;  // graceful fail -> diagnostic absmax

  hipFuncSetAttribute((const void*)gemm1_8ph,
                      hipFuncAttributeMaxDynamicSharedMemorySize, 131072);

  // hs fp32 -> bf16
  f32_to_bf16<<<(MR * HID) / (256 * 8), 256, 0, stream>>>(hs, hs16);
  // W1 transpose (vectorized; rows up to 8704 zero-padded)
  transpose_w64<<<dim3(NPAD1 / 64, HID / 64), 256, 0, stream>>>(w1, W1t, HID, PROJD);
  // GEMM1: 256^2 K-slice 8-phase; grid 16x34 = 544 (%8==0)
  gemm1_8ph<<<544, 512, 131072, stream>>>(hs16, W1t, b1, gateb, hbcb, dtsec,
                                          PROJD, HID, 34);
  // conv X-part with fused transpose dual-write (Xt overwrites W1t: dead)
  conv_x<<<dim3(SS / 64, HH, BB), 256, 0, stream>>>(hbcb, cw, X_lp, Xt);
  // conv B/C channels (256 channels = 32 chunks)
  conv_bc<<<(BB * SS * 32) / 256, 256, 0, stream>>>(hbcb, cw, Bc, Cc);
  // fused dt softplus + per-chunk cumsum
  dt_cumsum<<<BB * HH, 256, 0, stream>>>(dtsec, dtb, alog, dtv, cumA);
  // B transpose for states-pass fragments (4 MB)
  transpose_bf16<<<dim3(NST / 32, SS / 32, BB), 256, 0, stream>>>(Bc, Btc, SS, NST);
  // SSD pass 1: Y_diag + D residual + chunk states (ybb overwrites hbcb)
  ssd1<<<dim3(HH, NC, BB), 256, 0, stream>>>(Cc, Bc, Btc, Xt, X_lp, Dv,
                                             cumA, dtv, ybb, statesb);
  // inter-chunk recurrence, in place
  reck<<<(BB * HH * PP * NST) / 256, 256, 0, stream>>>(statesb, cumA);
  // SSD pass 2: Y_off only (live waves RMW)
  ssd2<<<dim3(HH, NC, BB), 256, 0, stream>>>(Cc, statesb, cumA, ybb);
  // W2 transpose into region E (states dead after ssd2)
  transpose_w64<<<dim3(HID / 64, INTER / 64), 256, 0, stream>>>(w2, W2t, INTER, HID);
  // gate + RMSNorm (xgn overwrites X_lp: dead after ssd2)
  gatenorm<<<MR, 256, 0, stream>>>(ybb, gateb, nw, xgn);
  // GEMM2 (proven R4): grid 16*32 = 512 (%8==0)
  gemm2_r4<<<512, 256, 0, stream>>>(xgn, W2t, b2, out, HID, INTER, 16);
}

// Round 15
// 486.601 us; speedup vs baseline: 1.0448x; 1.0226x over previous
//
#include <hip/hip_runtime.h>

// ---------------- dims ----------------
constexpr int HH    = 64;     // heads
constexpr int PP    = 64;     // head dim
constexpr int HID   = 2048;
constexpr int NST   = 128;    // state dim
constexpr int LCC   = 256;    // chunk len
constexpr int INTER = 4096;
constexpr int CONVD = 4352;
constexpr int PROJD = 8512;
constexpr int BB    = 4;
constexpr int SS    = 1024;
constexpr int NC    = 4;      // chunks
constexpr int MR    = BB * SS;      // 4096 rows
constexpr int NPAD1 = 8576;         // PROJD padded to 128 (GEMM1 tiles: 67)

typedef unsigned short u16;
typedef __bf16 bf16x8_t __attribute__((ext_vector_type(8)));
typedef short short8 __attribute__((ext_vector_type(8)));
typedef float f32x4 __attribute__((ext_vector_type(4)));
typedef u16 u16x4 __attribute__((ext_vector_type(4)));

__device__ __forceinline__ float bf2f(u16 u) {
  union { unsigned int i; float f; } v; v.i = ((unsigned int)u) << 16; return v.f;
}
__device__ __forceinline__ u16 f2bf(float f) {
  union { float f; unsigned int i; } v; v.f = f;
  unsigned int r = v.i + 0x7FFFu + ((v.i >> 16) & 1u);
  return (u16)(r >> 16);
}
__device__ __forceinline__ f32x4 mfma16(short8 a, short8 b, f32x4 c) {
  union U { short8 s; bf16x8_t b; };
  U ua; ua.s = a; U ub; ub.s = b;
  return __builtin_amdgcn_mfma_f32_16x16x32_bf16(ua.b, ub.b, c, 0, 0, 0);
}
__device__ __forceinline__ float sigm(float x) { return 1.f / (1.f + __expf(-x)); }
__device__ __forceinline__ void gload16(const u16* g, u16* l) {
  __builtin_amdgcn_global_load_lds(
      (const __attribute__((address_space(1))) void*)g,
      (__attribute__((address_space(3))) void*)l, 16, 0, 0);
}

// ---------------- fp32 -> bf16 convert (hs) ------------------------------------
__global__ void f32_to_bf16(const float* __restrict__ in, u16* __restrict__ out) {
  int i = (blockIdx.x * 256 + threadIdx.x) * 8;
  float4 a = *(const float4*)&in[i];
  float4 b = *(const float4*)&in[i + 4];
  short8 v;
  v[0] = (short)f2bf(a.x); v[1] = (short)f2bf(a.y);
  v[2] = (short)f2bf(a.z); v[3] = (short)f2bf(a.w);
  v[4] = (short)f2bf(b.x); v[5] = (short)f2bf(b.y);
  v[6] = (short)f2bf(b.z); v[7] = (short)f2bf(b.w);
  *(short8*)&out[i] = v;
}

// ---------------- vectorized weight transpose: in [K][N] f32 -> out [Npad][K] bf16
__global__ __launch_bounds__(256) void transpose_w64(
    const float* __restrict__ in, u16* __restrict__ out, int K_, int N_) {
  const int n0 = blockIdx.x * 64, k0 = blockIdx.y * 64;
  const int t = threadIdx.x;
  __shared__ u16 tile[64][72];   // [n][k]
#pragma unroll
  for (int i = 0; i < 4; ++i) {
    int idx = i * 256 + t;            // 0..1023
    int kk = idx >> 4;                // 0..63
    int nc = (idx & 15) * 4;          // 0..60
    int n = n0 + nc;
    float4 v = make_float4(0.f, 0.f, 0.f, 0.f);
    if (n + 3 < N_) v = *(const float4*)&in[(size_t)(k0 + kk) * N_ + n];
    tile[nc + 0][kk] = f2bf(v.x);
    tile[nc + 1][kk] = f2bf(v.y);
    tile[nc + 2][kk] = f2bf(v.z);
    tile[nc + 3][kk] = f2bf(v.w);
  }
  __syncthreads();
#pragma unroll
  for (int i = 0; i < 2; ++i) {
    int idx = i * 256 + t;            // 0..511
    int nn = idx >> 3;                // 0..63
    int kc = (idx & 7) * 8;
    *(short8*)&out[(size_t)(n0 + nn) * K_ + k0 + kc] =
        *(const short8*)&tile[nn][kc];
  }
}

// ---------------- generic bf16 transpose (B only): in [R][C] -> out [C][R] -----
__global__ void transpose_bf16(const u16* __restrict__ in, u16* __restrict__ out,
                               int R, int C) {
  int bt = blockIdx.z;
  const u16* ip = in + (size_t)bt * R * C;
  u16* op = out + (size_t)bt * R * C;
  __shared__ u16 tile[32][33];
  int r0 = blockIdx.y * 32, c0 = blockIdx.x * 32, t = threadIdx.x;
#pragma unroll
  for (int i = 0; i < 4; ++i) {
    int flat = i * 256 + t; int rr = flat >> 5, cc = flat & 31;
    tile[rr][cc] = ip[(size_t)(r0 + rr) * C + c0 + cc];
  }
  __syncthreads();
#pragma unroll
  for (int i = 0; i < 4; ++i) {
    int flat = i * 256 + t; int cc = flat >> 5, rr = flat & 31;
    op[(size_t)(c0 + cc) * R + r0 + rr] = tile[rr][cc];
  }
}

// ---------------- GEMM (proven R4): C = A[M][K] @ Bt[N][K]^T + bias ------------
// 128x128 tile, BK=64, 4 waves (2x2), global_load_lds w16, T2 XOR swizzle.
// MODE 0: out fp32 (GEMM2).  MODE 1: split bf16 out (GEMM1).
template <int MODE>
__global__ __launch_bounds__(256) void gemm_bt(
    const u16* __restrict__ A, const u16* __restrict__ Bt,
    const float* __restrict__ bias, void* __restrict__ Cp,
    u16* __restrict__ hbcb, u16* __restrict__ dtsec,
    int M, int Nreal, int K, int gx) {
  __shared__ __align__(16) u16 As[128 * 64];
  __shared__ __align__(16) u16 Bs[128 * 64];
  const int nwg = gridDim.x, bid = blockIdx.x;
  const int q = nwg >> 3;
  const int swz = (bid & 7) * q + (bid >> 3);
  const int bx = swz % gx, by = swz / gx;
  const int m0 = by * 128, n0 = bx * 128;
  const int t = threadIdx.x;
  const int w = t >> 6, lane = t & 63, lr = lane & 15, lhi = lane >> 4;
  const int wr = (w >> 1) * 64, wc = (w & 1) * 64;
  const int srow = t >> 3;
  const int sw_scol = (((t & 7) ^ ((t >> 3) & 7)) << 3);
  const u16* ga = A + (size_t)(m0 + srow) * K + sw_scol;
  const u16* gb = Bt + (size_t)(n0 + srow) * K + sw_scol;
  u16* la = As + w * 512;
  u16* lb = Bs + w * 512;
  const int swz_rd = (lr & 7) << 3;
  f32x4 acc[4][4] = {};
  for (int k0 = 0; k0 < K; k0 += 64) {
    __syncthreads();
#pragma unroll
    for (int j = 0; j < 4; ++j) {
      gload16(ga + (size_t)(j * 32) * K + k0, la + j * 2048);
      gload16(gb + (size_t)(j * 32) * K + k0, lb + j * 2048);
    }
    __syncthreads();
#pragma unroll
    for (int ks = 0; ks < 2; ++ks) {
      const int cs = (ks * 32 + lhi * 8) ^ swz_rd;
      short8 af[4], bfv[4];
#pragma unroll
      for (int mi = 0; mi < 4; ++mi)
        af[mi] = *(const short8*)&As[(wr + mi * 16 + lr) * 64 + cs];
#pragma unroll
      for (int ni = 0; ni < 4; ++ni)
        bfv[ni] = *(const short8*)&Bs[(wc + ni * 16 + lr) * 64 + cs];
#pragma unroll
      for (int mi = 0; mi < 4; ++mi)
#pragma unroll
        for (int ni = 0; ni < 4; ++ni)
          acc[mi][ni] = mfma16(af[mi], bfv[ni], acc[mi][ni]);
    }
  }
#pragma unroll
  for (int ni = 0; ni < 4; ++ni) {
    int col = n0 + wc + ni * 16 + lr;
    if (col >= Nreal) continue;
    float bv = bias[col];
#pragma unroll
    for (int mi = 0; mi < 4; ++mi)
#pragma unroll
      for (int j = 0; j < 4; ++j) {
        int row = m0 + wr + mi * 16 + lhi * 4 + j;
        float v = acc[mi][ni][j] + bv;
        if (MODE == 0) {
          ((float*)Cp)[(size_t)row * Nreal + col] = v;
        } else {
          u16 o = f2bf(v);
          if (col < INTER)              ((u16*)Cp)[(size_t)row * INTER + col] = o;
          else if (col < INTER + CONVD) hbcb[(size_t)row * CONVD + (col - INTER)] = o;
          else                          dtsec[(size_t)row * HH + (col - INTER - CONVD)] = o;
        }
      }
  }
}

// ---------------- conv1d X-part + SiLU, fused transpose dual-write -------------
__global__ __launch_bounds__(256) void conv_x(
    const u16* __restrict__ hbcb, const float* __restrict__ convw,
    u16* __restrict__ X_lp, u16* __restrict__ Xt) {
  const int st = blockIdx.x, h = blockIdx.y, b = blockIdx.z;
  const int s0 = st * 64;
  const int t = threadIdx.x;
  const int bh = b * HH + h;
  __shared__ u16 tile[64][72];   // [s][p]
#pragma unroll
  for (int i = 0; i < 2; ++i) {
    int idx = i * 256 + t;       // 0..511
    int s = idx >> 3;            // 0..63
    int pc = (idx & 7) * 8;
    short8 v[4];
#pragma unroll
    for (int k = 0; k < 4; ++k) {
      int ss = s0 + s - 3 + k;
      if (ss >= 0)
        v[k] = *(const short8*)&hbcb[(size_t)(b * SS + ss) * CONVD + h * 64 + pc];
      else
        v[k] = short8{0, 0, 0, 0, 0, 0, 0, 0};
    }
    short8 o;
#pragma unroll
    for (int j = 0; j < 8; ++j) {
      float4 wj = *(const float4*)&convw[(h * 64 + pc + j) * 4];
      float a = bf2f((u16)v[0][j]) * wj.x + bf2f((u16)v[1][j]) * wj.y +
                bf2f((u16)v[2][j]) * wj.z + bf2f((u16)v[3][j]) * wj.w;
      o[j] = (short)f2bf(a * sigm(a));
    }
    *(short8*)&X_lp[((size_t)bh * SS + s0 + s) * PP + pc] = o;
    *(short8*)&tile[s][pc] = o;
  }
  __syncthreads();
#pragma unroll
  for (int i = 0; i < 2; ++i) {
    int idx = i * 256 + t;
    int p = idx >> 3;            // 0..63
    int sc = (idx & 7) * 8;
    short8 o;
#pragma unroll
    for (int j = 0; j < 8; ++j) o[j] = (short)tile[sc + j][p];
    *(short8*)&Xt[((size_t)bh * PP + p) * SS + s0 + sc] = o;
  }
}

// ---------------- conv1d B/C channels (256 ch = 32 chunks of 8) + SiLU ---------
__global__ __launch_bounds__(256) void conv_bc(
    const u16* __restrict__ hbcb, const float* __restrict__ convw,
    u16* __restrict__ Bc, u16* __restrict__ Cc) {
  int idx = blockIdx.x * 256 + threadIdx.x;   // < BB*SS*32
  int c8 = idx & 31;
  int rest = idx >> 5;
  int s = rest & (SS - 1);
  int b = rest >> 10;
  int ch = INTER + c8 * 8;                    // [4096, 4352)
  short8 v[4];
#pragma unroll
  for (int k = 0; k < 4; ++k) {
    int ss = s - 3 + k;
    if (ss >= 0) v[k] = *(const short8*)&hbcb[(size_t)(b * SS + ss) * CONVD + ch];
    else         v[k] = short8{0, 0, 0, 0, 0, 0, 0, 0};
  }
  short8 o;
#pragma unroll
  for (int j = 0; j < 8; ++j) {
    float4 wj = *(const float4*)&convw[(ch + j) * 4];
    float a = bf2f((u16)v[0][j]) * wj.x + bf2f((u16)v[1][j]) * wj.y +
              bf2f((u16)v[2][j]) * wj.z + bf2f((u16)v[3][j]) * wj.w;
    o[j] = (short)f2bf(a * sigm(a));
  }
  if (ch < INTER + NST)
    *(short8*)&Bc[((size_t)(b * SS + s)) * NST + (ch - INTER)] = o;
  else
    *(short8*)&Cc[((size_t)(b * SS + s)) * NST + (ch - INTER - NST)] = o;
}

// ---------------- fused dt softplus + per-chunk cumsum (wave scan) -------------
__global__ __launch_bounds__(256) void dt_cumsum(
    const u16* __restrict__ dtsec, const float* __restrict__ dtb,
    const float* __restrict__ alog, float* __restrict__ dtv,
    float* __restrict__ cumA) {
  const int bh = blockIdx.x;
  const int b = bh >> 6, h = bh & 63;
  const int t = threadIdx.x, w = t >> 6, lane = t & 63;
  const float na = -__expf(alog[h]);
  const float db = dtb[h];
  size_t base = (size_t)bh * SS + w * LCC;
  float d[4];
#pragma unroll
  for (int j = 0; j < 4; ++j) {
    int s = w * LCC + lane * 4 + j;
    float x = bf2f(dtsec[(size_t)(b * SS + s) * HH + h]) + db;
    d[j] = (x > 20.f) ? x : log1pf(__expf(x));
  }
  *(float4*)&dtv[base + lane * 4] = make_float4(d[0], d[1], d[2], d[3]);
  float a0 = na * d[0];
  float s1 = a0 + na * d[1];
  float s2 = s1 + na * d[2];
  float tot = s2 + na * d[3];
  float run = tot;
#pragma unroll
  for (int off = 1; off < 64; off <<= 1) {
    float u = __shfl_up(run, off);
    if (lane >= off) run += u;
  }
  float excl = run - tot;
  float4 o; o.x = excl + a0; o.y = excl + s1; o.z = excl + s2; o.w = excl + tot;
  *(float4*)&cumA[base + lane * 4] = o;
}

// ---------------- SSD pass 1: Y_diag + D residual + chunk states (decay-skip) --
__global__ __launch_bounds__(256) void ssd1(
    const u16* __restrict__ Cc, const u16* __restrict__ Bc,
    const u16* __restrict__ Btc, const u16* __restrict__ Xt,
    const u16* __restrict__ X_lp, const float* __restrict__ Dv,
    const float* __restrict__ cumA, const float* __restrict__ dtv,
    u16* __restrict__ ybb, u16* __restrict__ statesb) {
  const int h = blockIdx.x, c = blockIdx.y, b = blockIdx.z;
  const int bh = b * HH + h, s0 = c * LCC;
  const int t = threadIdx.x, w = t >> 6, lane = t & 63, lr = lane & 15, lhi = lane >> 4;
  __shared__ float cumA_s[LCC], dtv_s[LCC], w_s[LCC];
  __shared__ __align__(16) u16 Mld[4][64 * 72];
  cumA_s[t] = cumA[(size_t)bh * SS + s0 + t];
  dtv_s[t] = dtv[(size_t)bh * SS + s0 + t];
  __syncthreads();
  w_s[t] = dtv_s[t] * __expf(cumA_s[LCC - 1] - cumA_s[t]);
  __syncthreads();

  f32x4 Yacc[4][4] = {};
  u16* Mw = &Mld[w][0];
  for (int st = 0; st <= w; ++st) {
    if (st < w && (cumA_s[w * 64] - cumA_s[st * 64 + 63] < -30.f)) continue;
    f32x4 G[4][4] = {};
#pragma unroll
    for (int ks = 0; ks < 4; ++ks) {
      short8 cf[4], bfr[4];
#pragma unroll
      for (int mi = 0; mi < 4; ++mi)
        cf[mi] = *(const short8*)&Cc[((size_t)(b * SS + s0 + w * 64 + mi * 16 + lr)) * NST + ks * 32 + lhi * 8];
#pragma unroll
      for (int ni = 0; ni < 4; ++ni)
        bfr[ni] = *(const short8*)&Bc[((size_t)(b * SS + s0 + st * 64 + ni * 16 + lr)) * NST + ks * 32 + lhi * 8];
#pragma unroll
      for (int mi = 0; mi < 4; ++mi)
#pragma unroll
        for (int ni = 0; ni < 4; ++ni)
          G[mi][ni] = mfma16(cf[mi], bfr[ni], G[mi][ni]);
    }
#pragma unroll
    for (int mi = 0; mi < 4; ++mi)
#pragma unroll
      for (int ni = 0; ni < 4; ++ni) {
        int sloc = st * 64 + ni * 16 + lr;
        float ds = dtv_s[sloc];
#pragma unroll
        for (int j = 0; j < 4; ++j) {
          int l = w * 64 + mi * 16 + lhi * 4 + j;
          float v = (sloc <= l) ? G[mi][ni][j] * __expf(cumA_s[l] - cumA_s[sloc]) * ds : 0.f;
          Mw[(mi * 16 + lhi * 4 + j) * 72 + ni * 16 + lr] = f2bf(v);
        }
      }
#pragma unroll
    for (int kh = 0; kh < 2; ++kh) {
      short8 xf[4];
#pragma unroll
      for (int ni = 0; ni < 4; ++ni)
        xf[ni] = *(const short8*)&Xt[((size_t)bh * PP + ni * 16 + lr) * SS + s0 + st * 64 + kh * 32 + lhi * 8];
#pragma unroll
      for (int mi = 0; mi < 4; ++mi) {
        short8 mf = *(const short8*)&Mw[(mi * 16 + lr) * 72 + kh * 32 + lhi * 8];
#pragma unroll
        for (int ni = 0; ni < 4; ++ni)
          Yacc[mi][ni] = mfma16(mf, xf[ni], Yacc[mi][ni]);
      }
    }
  }
  const float Dh = Dv[h];
#pragma unroll
  for (int mi = 0; mi < 4; ++mi)
#pragma unroll
    for (int ni = 0; ni < 4; ++ni)
#pragma unroll
      for (int j = 0; j < 4; ++j) {
        int l = w * 64 + mi * 16 + lhi * 4 + j;
        int p = ni * 16 + lr;
        float xv = bf2f(X_lp[((size_t)bh * SS + s0 + l) * PP + p]);
        ybb[((size_t)(b * SS + s0 + l)) * INTER + h * PP + p] =
            f2bf(Yacc[mi][ni][j] + Dh * xv);
      }
  f32x4 Sacc[4][2] = {};
  for (int ks = 0; ks < 8; ++ks) {
    if (cumA_s[LCC - 1] - cumA_s[ks * 32 + 31] < -30.f) continue;
    f32x4 w0 = *(const f32x4*)&w_s[ks * 32 + lhi * 8];
    f32x4 w1 = *(const f32x4*)&w_s[ks * 32 + lhi * 8 + 4];
    short8 bfr[2];
#pragma unroll
    for (int nj = 0; nj < 2; ++nj) {
      short8 br = *(const short8*)&Btc[((size_t)b * NST + w * 32 + nj * 16 + lr) * SS + s0 + ks * 32 + lhi * 8];
      short8 bs;
      bs[0] = (short)f2bf(bf2f((u16)br[0]) * w0[0]);
      bs[1] = (short)f2bf(bf2f((u16)br[1]) * w0[1]);
      bs[2] = (short)f2bf(bf2f((u16)br[2]) * w0[2]);
      bs[3] = (short)f2bf(bf2f((u16)br[3]) * w0[3]);
      bs[4] = (short)f2bf(bf2f((u16)br[4]) * w1[0]);
      bs[5] = (short)f2bf(bf2f((u16)br[5]) * w1[1]);
      bs[6] = (short)f2bf(bf2f((u16)br[6]) * w1[2]);
      bs[7] = (short)f2bf(bf2f((u16)br[7]) * w1[3]);
      bfr[nj] = bs;
    }
#pragma unroll
    for (int mi = 0; mi < 4; ++mi) {
      short8 af = *(const short8*)&Xt[((size_t)bh * PP + mi * 16 + lr) * SS + s0 + ks * 32 + lhi * 8];
#pragma unroll
      for (int nj = 0; nj < 2; ++nj)
        Sacc[mi][nj] = mfma16(af, bfr[nj], Sacc[mi][nj]);
    }
  }
#pragma unroll
  for (int mi = 0; mi < 4; ++mi)
#pragma unroll
    for (int nj = 0; nj < 2; ++nj)
#pragma unroll
      for (int j = 0; j < 4; ++j) {
        int p = mi * 16 + lhi * 4 + j;
        int n = w * 32 + nj * 16 + lr;
        statesb[((((size_t)b * NC + c) * HH + h) * PP + p) * NST + n] = f2bf(Sacc[mi][nj][j]);
      }
}

// ---------------- inter-chunk recurrence (IN PLACE: states -> prev) ------------
__global__ void reck(u16* __restrict__ statesb, const float* __restrict__ cumA) {
  int idx = blockIdx.x * 256 + threadIdx.x;  // < BB*HH*PP*NST
  int n = idx & 127, p = (idx >> 7) & 63, bh = idx >> 13;
  int b = bh >> 6, h = bh & 63;
  float prev = 0.f;
#pragma unroll
  for (int c2 = 0; c2 < NC; ++c2) {
    size_t si = ((((size_t)b * NC + c2) * HH + h) * PP + p) * NST + n;
    float s = bf2f(statesb[si]);           // read BEFORE overwrite
    statesb[si] = f2bf(prev);
    float tot = cumA[(size_t)bh * SS + c2 * LCC + (LCC - 1)];
    prev = prev * __expf(tot) + s;
  }
}

// ---------------- SSD pass 2: Y_off only (dead waves exit; live RMW) -----------
__global__ __launch_bounds__(256) void ssd2(
    const u16* __restrict__ Cc, const u16* __restrict__ prevb,
    const float* __restrict__ cumA, u16* __restrict__ ybb) {
  const int h = blockIdx.x, c = blockIdx.y, b = blockIdx.z;
  const int bh = b * HH + h, s0 = c * LCC;
  const int t = threadIdx.x, w = t >> 6, lane = t & 63, lr = lane & 15, lhi = lane >> 4;
  __shared__ float cumA_s[LCC];
  cumA_s[t] = cumA[(size_t)bh * SS + s0 + t];
  __syncthreads();
  if (cumA_s[w * 64] <= -30.f) return;
  f32x4 acc[4][4] = {};
  const size_t stbase = (((size_t)b * NC + c) * HH + h) * PP;
#pragma unroll
  for (int ks = 0; ks < 4; ++ks) {
    short8 sf[4];
#pragma unroll
    for (int pj = 0; pj < 4; ++pj)
      sf[pj] = *(const short8*)&prevb[(stbase + pj * 16 + lr) * NST + ks * 32 + lhi * 8];
#pragma unroll
    for (int mi = 0; mi < 4; ++mi) {
      short8 cf = *(const short8*)&Cc[((size_t)(b * SS + s0 + w * 64 + mi * 16 + lr)) * NST + ks * 32 + lhi * 8];
#pragma unroll
      for (int pj = 0; pj < 4; ++pj)
        acc[mi][pj] = mfma16(cf, sf[pj], acc[mi][pj]);
    }
  }
#pragma unroll
  for (int mi = 0; mi < 4; ++mi)
#pragma unroll
    for (int pj = 0; pj < 4; ++pj)
#pragma unroll
      for (int j = 0; j < 4; ++j) {
        int l = w * 64 + mi * 16 + lhi * 4 + j;
        int p = pj * 16 + lr;
        size_t yi = ((size_t)(b * SS + s0 + l)) * INTER + h * PP + p;
        float cur = bf2f(ybb[yi]);
        ybb[yi] = f2bf(cur + acc[mi][pj][j] * __expf(cumA_s[l]));
      }
}

// ---------------- gate (SiLU) + RMSNorm -> bf16 --------------------------------
__global__ __launch_bounds__(256) void gatenorm(
    const u16* __restrict__ ybb, const u16* __restrict__ gateb,
    const float* __restrict__ nw, u16* __restrict__ xgn) {
  const int r = blockIdx.x, t = threadIdx.x;
  const int w = t >> 6, lane = t & 63;
  float xg[16];
  float s2 = 0.f;
#pragma unroll
  for (int i = 0; i < 2; ++i) {
    int col = (i * 256 + t) * 8;
    short8 yv = *(const short8*)&ybb[(size_t)r * INTER + col];
    short8 gv = *(const short8*)&gateb[(size_t)r * INTER + col];
#pragma unroll
    for (int j = 0; j < 8; ++j) {
      float g = bf2f((u16)gv[j]);
      float o = bf2f((u16)yv[j]) * g * sigm(g);
      xg[i * 8 + j] = o;
      s2 += o * o;
    }
  }
#pragma unroll
  for (int off = 32; off > 0; off >>= 1) s2 += __shfl_down(s2, off);
  __shared__ float red[4];
  if (lane == 0) red[w] = s2;
  __syncthreads();
  float rstd = rsqrtf((red[0] + red[1] + red[2] + red[3]) * (1.f / INTER) + 1e-5f);
#pragma unroll
  for (int i = 0; i < 2; ++i) {
    int col = (i * 256 + t) * 8;
    float4 n0 = *(const float4*)&nw[col];
    float4 n1 = *(const float4*)&nw[col + 4];
    short8 o;
    o[0] = (short)f2bf(xg[i * 8 + 0] * rstd * n0.x);
    o[1] = (short)f2bf(xg[i * 8 + 1] * rstd * n0.y);
    o[2] = (short)f2bf(xg[i * 8 + 2] * rstd * n0.z);
    o[3] = (short)f2bf(xg[i * 8 + 3] * rstd * n0.w);
    o[4] = (short)f2bf(xg[i * 8 + 4] * rstd * n1.x);
    o[5] = (short)f2bf(xg[i * 8 + 5] * rstd * n1.y);
    o[6] = (short)f2bf(xg[i * 8 + 6] * rstd * n1.z);
    o[7] = (short)f2bf(xg[i * 8 + 7] * rstd * n1.w);
    *(short8*)&xgn[(size_t)r * INTER + col] = o;
  }
}

// ---------------- launch -------------------------------------------------------
extern "C" void kernel_launch(void* const* d_in, const int* in_sizes, int n_in,
                              void* d_out, int out_size, void* d_ws, size_t ws_size,
                              hipStream_t stream) {
  const float* hs   = (const float*)d_in[0];
  const float* w1   = (const float*)d_in[1];
  const float* b1   = (const float*)d_in[2];
  const float* cw   = (const float*)d_in[3];
  const float* dtb  = (const float*)d_in[4];
  const float* alog = (const float*)d_in[5];
  const float* Dv   = (const float*)d_in[6];
  const float* nw   = (const float*)d_in[7];
  const float* w2   = (const float*)d_in[8];
  const float* b2   = (const float*)d_in[9];
  float* out = (float*)d_out;

  char* ws = (char*)d_ws;
  size_t off = 0;
  auto alloc = [&](size_t bytes) -> char* {
    char* p = ws + off;
    off += (bytes + 255) & ~(size_t)255;
    return p;
  };
  // region A: W1t (35.1MB) -> Xt (33.6MB) after GEMM1
  char* regA = alloc((size_t)NPAD1 * HID * 2);
  u16* W1t = (u16*)regA;
  u16* Xt  = (u16*)regA;
  // region B: gate (bf16) [GEMM1 .. gatenorm]
  u16* gateb = (u16*)alloc((size_t)MR * INTER * 2);
  // region C: hbc (35.7MB) -> y bf16 (33.6MB) after conv
  char* regC = alloc((size_t)MR * CONVD * 2);
  u16* hbcb = (u16*)regC;
  u16* ybb  = (u16*)regC;
  // region D: X_lp -> xgn after ssd2
  char* regD = alloc((size_t)BB * HH * SS * PP * 2);
  u16* X_lp = (u16*)regD;
  u16* xgn  = (u16*)regD;
  // region E: states bf16 (in-place -> prev) -> W2t after ssd2
  char* regE = alloc((size_t)BB * NC * HH * PP * NST * 2);
  u16* statesb = (u16*)regE;
  u16* W2t     = (u16*)regE;
  // small buffers
  u16*   hs16  = (u16*)alloc((size_t)MR * HID * 2);
  u16*   dtsec = (u16*)alloc((size_t)MR * HH * 2);
  u16*   Bc    = (u16*)alloc((size_t)BB * SS * NST * 2);
  u16*   Cc    = (u16*)alloc((size_t)BB * SS * NST * 2);
  u16*   Btc   = (u16*)alloc((size_t)BB * NST * SS * 2);
  float* dtv   = (float*)alloc((size_t)BB * HH * SS * 4);
  float* cumA  = (float*)alloc((size_t)BB * HH * SS * 4);

  if (off > ws_size) return;  // graceful fail -> diagnostic absmax

  // hs fp32 -> bf16
  f32_to_bf16<<<(MR * HID) / (256 * 8), 256, 0, stream>>>(hs, hs16);
  // W1 transpose (vectorized)
  transpose_w64<<<dim3(NPAD1 / 64, HID / 64), 256, 0, stream>>>(w1, W1t, HID, PROJD);
  // GEMM1 (proven R4): split epilogue -> gateb / hbcb / dtsec (grid 2144, %8==0)
  gemm_bt<1><<<67 * 32, 256, 0, stream>>>(hs16, W1t, b1, gateb, hbcb, dtsec,
                                          MR, PROJD, HID, 67);
  // conv X-part with fused transpose dual-write (Xt overwrites W1t: dead)
  conv_x<<<dim3(SS / 64, HH, BB), 256, 0, stream>>>(hbcb, cw, X_lp, Xt);
  // conv B/C channels (256 channels = 32 chunks)
  conv_bc<<<(BB * SS * 32) / 256, 256, 0, stream>>>(hbcb, cw, Bc, Cc);
  // fused dt softplus + per-chunk cumsum
  dt_cumsum<<<BB * HH, 256, 0, stream>>>(dtsec, dtb, alog, dtv, cumA);
  // B transpose for states-pass fragments (4 MB)
  transpose_bf16<<<dim3(NST / 32, SS / 32, BB), 256, 0, stream>>>(Bc, Btc, SS, NST);
  // SSD pass 1: Y_diag + D residual + chunk states (ybb overwrites hbcb)
  ssd1<<<dim3(HH, NC, BB), 256, 0, stream>>>(Cc, Bc, Btc, Xt, X_lp, Dv,
                                             cumA, dtv, ybb, statesb);
  // inter-chunk recurrence, in place
  reck<<<(BB * HH * PP * NST) / 256, 256, 0, stream>>>(statesb, cumA);
  // SSD pass 2: Y_off only (live waves RMW)
  ssd2<<<dim3(HH, NC, BB), 256, 0, stream>>>(Cc, statesb, cumA, ybb);
  // W2 transpose into region E (states dead after ssd2)
  transpose_w64<<<dim3(HID / 64, INTER / 64), 256, 0, stream>>>(w2, W2t, INTER, HID);
  // gate + RMSNorm (xgn overwrites X_lp: dead after ssd2)
  gatenorm<<<MR, 256, 0, stream>>>(ybb, gateb, nw, xgn);
  // GEMM2 (proven R4): grid 16*32 = 512 (%8==0)
  gemm_bt<0><<<16 * 32, 256, 0, stream>>>(xgn, W2t, b2, out, nullptr, nullptr,
                                          MR, HID, INTER, 16);
}